// Round 8
// baseline (2486.526 us; speedup 1.0000x reference)
//
#include <hip/hip_runtime.h>
#include <stdint.h>

typedef unsigned short u16;
typedef unsigned int u32;
typedef __attribute__((ext_vector_type(8))) short bf16x8;
typedef __attribute__((ext_vector_type(8))) unsigned short u16x8;
typedef __attribute__((ext_vector_type(2))) unsigned int u32x2;
typedef __attribute__((ext_vector_type(4))) float f32x4;

#define LB256 __launch_bounds__(256, 2)

// ---- problem dims ----
#define BB 4
#define NX 1024
#define NC 154
#define NT 1178
#define NTP 1184   // padded t stride for V^T (16B-aligned rows)
#define DD 1536
#define HH 24
#define MHD 6144
#define NQKV 4608
#define NMOD 9216
#define KSPL 6

__device__ __forceinline__ int imin(int a, int b) { return a < b ? a : b; }

__device__ __forceinline__ u16 f2bf(float f) {
  u32 u = __float_as_uint(f);
  u32 r = (u + 0x7fffu + ((u >> 16) & 1u)) >> 16;
  return (u16)r;
}

__device__ __forceinline__ float bf2f(u16 v) {
  u32 u = ((u32)v) << 16;
  return __uint_as_float(u);
}

__device__ __forceinline__ float gelu_t(float x) {
  float x2 = x * x;
  float t = tanhf(0.7978845608028654f * x * (1.f + 0.044715f * x2));
  return 0.5f * x * (1.f + t);
}

__device__ __forceinline__ f32x4 fzero4() {
  f32x4 z; z[0] = 0.f; z[1] = 0.f; z[2] = 0.f; z[3] = 0.f; return z;
}

// async global->LDS, 16B per lane; LDS dest = wave-uniform base + lane*16
__device__ __forceinline__ void glds16(const u16* g, u16* l) {
  __builtin_amdgcn_global_load_lds(
      (const __attribute__((address_space(1))) void*)g,
      (__attribute__((address_space(3))) void*)l, 16, 0, 0);
}

#define WAITV4 asm volatile("s_waitcnt vmcnt(4)" ::: "memory")
#define WAITV0 asm volatile("s_waitcnt vmcnt(0)" ::: "memory")
#define SCHEDB __builtin_amdgcn_sched_barrier(0)

// ---- weight transpose + f32->bf16: W[K][N] -> Wt[N][K] ----
__global__ void k_transpose(const float* __restrict__ W, u16* __restrict__ Wt, int K, int N) {
  __shared__ float tile[32][33];
  int n0 = blockIdx.x * 32, k0 = blockIdx.y * 32;
  int tx = threadIdx.x & 31, ty = threadIdx.x >> 5;  // 32 x 8
#pragma unroll
  for (int j = 0; j < 32; j += 8)
    tile[ty + j][tx] = W[(size_t)(k0 + ty + j) * N + n0 + tx];
  __syncthreads();
#pragma unroll
  for (int j = 0; j < 32; j += 8)
    Wt[(size_t)(n0 + ty + j) * K + k0 + tx] = f2bf(tile[tx][ty + j]);
}

// ---- mod = silu(vec) @ w_mod + b_mod : split-K partials (deterministic) ----
__global__ void k_mod_part(const float* __restrict__ vec, const float* __restrict__ w_mod,
                           float* __restrict__ part) {
  __shared__ float sv[BB][256];
  int n = blockIdx.x * 256 + threadIdx.x;
  int kb = blockIdx.y;
  int k0 = kb * 256;
  for (int i = threadIdx.x; i < BB * 256; i += 256) {
    int b = i >> 8, kk = i & 255;
    float v = vec[b * DD + k0 + kk];
    sv[b][kk] = v / (1.f + __expf(-v));
  }
  __syncthreads();
  float a0 = 0.f, a1 = 0.f, a2 = 0.f, a3 = 0.f;
  for (int k = 0; k < 256; ++k) {
    float w = w_mod[(size_t)(k0 + k) * NMOD + n];
    a0 = fmaf(sv[0][k], w, a0);
    a1 = fmaf(sv[1][k], w, a1);
    a2 = fmaf(sv[2][k], w, a2);
    a3 = fmaf(sv[3][k], w, a3);
  }
  part[((size_t)kb * BB + 0) * NMOD + n] = a0;
  part[((size_t)kb * BB + 1) * NMOD + n] = a1;
  part[((size_t)kb * BB + 2) * NMOD + n] = a2;
  part[((size_t)kb * BB + 3) * NMOD + n] = a3;
}

__global__ void k_mod_red(const float* __restrict__ part, const float* __restrict__ b_mod,
                          float* __restrict__ mod) {
  int n = blockIdx.x * 256 + threadIdx.x;
  float bb = b_mod[n];
#pragma unroll
  for (int b = 0; b < BB; ++b) {
    float s = bb;
#pragma unroll
    for (int kb = 0; kb < KSPL; ++kb) s += part[((size_t)kb * BB + b) * NMOD + n];
    mod[b * NMOD + n] = s;
  }
}

// ---- LayerNorm (optionally modulated) f32 -> bf16 ----
__global__ LB256 void k_ln(const float* __restrict__ in, u16* __restrict__ out,
                           const float* __restrict__ modp, int sh_off, int sc_off,
                           int rows_per_b) {
  int row = blockIdx.x;
  int b = row / rows_per_b;
  const float* xr = in + (size_t)row * DD;
  float v[6];
  float s = 0.f, s2 = 0.f;
#pragma unroll
  for (int i = 0; i < 6; ++i) {
    float t = xr[threadIdx.x + 256 * i];
    v[i] = t; s += t; s2 += t * t;
  }
#pragma unroll
  for (int m = 32; m >= 1; m >>= 1) {
    s += __shfl_xor(s, m);
    s2 += __shfl_xor(s2, m);
  }
  __shared__ float red[8];
  int wid = threadIdx.x >> 6;
  if ((threadIdx.x & 63) == 0) { red[wid] = s; red[4 + wid] = s2; }
  __syncthreads();
  s = red[0] + red[1] + red[2] + red[3];
  s2 = red[4] + red[5] + red[6] + red[7];
  float mean = s * (1.f / (float)DD);
  float var = s2 * (1.f / (float)DD) - mean * mean;
  float rstd = rsqrtf(var + 1e-6f);
#pragma unroll
  for (int i = 0; i < 6; ++i) {
    int d = threadIdx.x + 256 * i;
    float y = (v[i] - mean) * rstd;
    if (modp) y = y * (1.f + modp[b * NMOD + sc_off + d]) + modp[b * NMOD + sh_off + d];
    out[(size_t)row * DD + d] = f2bf(y);
  }
}

// ---- 256x256x32 8-wave GEMM, 2 blocks/CU (64KB LDS double-buffer) ----
// Requires M%256==0, N%256==0, K%32==0. C = A(MxK) @ Bt(NxK)^T + bias.
// Per K-tile: WAITV0 + barrier, stage next tile (4 gload_lds/wave), 12 ds_read,
// 32 MFMA. Drain covered by sibling block (m114). Swizzle = 128x kernel's
// (row>>1)&3 involution, 0 conflicts measured. EPI: 0 bias->bf16 | 1 gelu->bf16
template <int EPI>
__global__ __launch_bounds__(512, 4) void k_gemm256(
    const u16* __restrict__ A, const u16* __restrict__ Bt,
    const float* __restrict__ bias, int N, int lda, int ldb, int kLen,
    u16* __restrict__ outp) {
  __shared__ __align__(16) u16 sm[2][16384];  // [buf][A 8K u16 | B 8K u16] = 64KB
  const int tid = threadIdx.x;
  const int lane = tid & 63;
  const int g = lane >> 4, r = lane & 15;
  const int wid = tid >> 6;
  const int wr = wid >> 2, wc = wid & 3;  // 2M x 4N wave grid

  // bijective XCD-aware tile remap (m204)
  const int gx = gridDim.x;
  const int nwg = gx * gridDim.y;
  int wg = blockIdx.y * gx + blockIdx.x;
  {
    int q = nwg >> 3, rr = nwg & 7;
    int xcd = wg & 7, sl = wg >> 3;
    wg = (xcd < rr ? xcd * (q + 1) : rr * (q + 1) + (xcd - rr) * q) + sl;
  }
  const int m0 = (wg / gx) * 256, n0 = (wg % gx) * 256;

  f32x4 acc[8][4];
#pragma unroll
  for (int i = 0; i < 8; ++i)
#pragma unroll
    for (int j = 0; j < 4; ++j) acc[i][j] = fzero4();

  // staging: per operand 16KB = 16 chunks of 1KB (16 rows x 64B each).
  // waves 0-3 stage A chunks c = (wid&3)*4+i ; waves 4-7 stage B likewise.
  // lane l -> row c*16 + l/4, phys slot l&3; logical slot = (l&3)^((row>>1)&3)
  // = (l&3)^((l>>3)&3) since c*16 is a multiple of 8.
  const bool isB = wid >= 4;
  const int rl = lane >> 2;
  const int slg = (lane & 3) ^ ((lane >> 3) & 3);
  const int cbase = (wid & 3) * 4;
  const u16* src = isB ? Bt : A;
  const int ld = isB ? ldb : lda;
  const int b0 = isB ? n0 : m0;
  const size_t g0 = (size_t)(b0 + cbase * 16 + rl) * ld + slg * 8;
  const int ldsb = (isB ? 8192 : 0) + cbase * 512;

#define STAGE256(BI, T)                                              \
  do {                                                               \
    _Pragma("unroll") for (int i = 0; i < 4; ++i)                    \
        glds16(src + g0 + (size_t)i * 16 * ld + (size_t)(T) * 32,    \
               &sm[BI][ldsb + i * 512]);                             \
  } while (0)

  const int nt = kLen >> 5;  // K-tiles of 32
  STAGE256(0, 0);

  // read-side swizzle: fragment row = base16 + r -> (row>>1)&3 == (r>>1)&3
  const int swz = (g ^ ((r >> 1) & 3)) * 8;
  int aOff[8], bOff[4];
#pragma unroll
  for (int mi = 0; mi < 8; ++mi) aOff[mi] = (wr * 128 + mi * 16 + r) * 32 + swz;
#pragma unroll
  for (int ni = 0; ni < 4; ++ni) bOff[ni] = 8192 + (wc * 64 + ni * 16 + r) * 32 + swz;

  for (int t = 0; t < nt; ++t) {
    WAITV0;                        // my 4 staging loads for tile t landed
    __builtin_amdgcn_s_barrier();  // all waves' tile-t data published;
    SCHEDB;                        // and all tile-(t-1) reads retired
    if (t + 1 < nt) STAGE256((t + 1) & 1, t + 1);
    const u16* bb = &sm[t & 1][0];
    bf16x8 af[8], bfv[4];
#pragma unroll
    for (int mi = 0; mi < 8; ++mi) af[mi] = *(const bf16x8*)(bb + aOff[mi]);
#pragma unroll
    for (int ni = 0; ni < 4; ++ni) bfv[ni] = *(const bf16x8*)(bb + bOff[ni]);
    __builtin_amdgcn_s_setprio(1);
#pragma unroll
    for (int mi = 0; mi < 8; ++mi)
#pragma unroll
      for (int ni = 0; ni < 4; ++ni)
        acc[mi][ni] = __builtin_amdgcn_mfma_f32_16x16x32_bf16(af[mi], bfv[ni], acc[mi][ni], 0, 0, 0);
    __builtin_amdgcn_s_setprio(0);
    SCHEDB;  // keep this tile's body ahead of next iteration's WAITV0
  }
#undef STAGE256

#pragma unroll
  for (int mi = 0; mi < 8; ++mi) {
#pragma unroll
    for (int ni = 0; ni < 4; ++ni) {
      const int col = n0 + wc * 64 + ni * 16 + r;
      const float bv = bias[col];
#pragma unroll
      for (int j = 0; j < 4; ++j) {
        const int row = m0 + wr * 128 + mi * 16 + g * 4 + j;
        const size_t off = (size_t)row * N + col;
        if constexpr (EPI == 0)
          outp[off] = f2bf(acc[mi][ni][j] + bv);
        else
          outp[off] = f2bf(gelu_t(acc[mi][ni][j] + bv));
      }
    }
  }
}

// ---- pipelined bf16 MFMA GEMM: C = A(MxK) @ Bt(NxK)^T (+bias), 128x128x32 tile
// 3-buffer LDS, counted vmcnt(4), single raw barrier per K-step, XOR-swizzled LDS.
// EPI: 0 bias->bf16 | 1 gelu(bias+acc)->bf16 | 2 resid+g*(acc+bias)->f32 |
//      3 resid+acc+bias->f32 | 4 acc->bf16 partial at outp + z*goff (split-K)
template <int EPI>
__global__ LB256 void k_gemm(const u16* __restrict__ A, const u16* __restrict__ Bt,
                             const float* __restrict__ bias, int M, int N,
                             int lda, int ldb, int kLen, int kzOff,
                             void* __restrict__ outp, const float* __restrict__ resid,
                             const float* __restrict__ modp, int goff, int rows_per_b) {
  __shared__ __align__(16) u16 sm[3 * 8192];  // 3 x (A 4096 + B 4096) u16 = 48 KB
  const int tid = threadIdx.x;
  const int lane = tid & 63;
  const int g = lane >> 4, r = lane & 15;
  const int wid = tid >> 6;

  // bijective XCD-aware tile remap (m204)
  const int gx = gridDim.x;
  const int nwg = gx * gridDim.y;
  int wg = blockIdx.y * gx + blockIdx.x;
  {
    int q = nwg >> 3, rr = nwg & 7;
    int xcd = wg & 7, sl = wg >> 3;
    wg = (xcd < rr ? xcd * (q + 1) : rr * (q + 1) + (xcd - rr) * q) + sl;
  }
  const int m0 = (wg / gx) * 128, n0 = (wg % gx) * 128;
  const int wm = (wid >> 1) * 64, wn = (wid & 1) * 64;

  A += (size_t)blockIdx.z * kzOff;
  Bt += (size_t)blockIdx.z * kzOff;

  f32x4 acc[4][4];
#pragma unroll
  for (int i = 0; i < 4; ++i)
#pragma unroll
    for (int j = 0; j < 4; ++j) acc[i][j] = fzero4();

  // staging geometry: tile (A or B) = 8 chunks of 1KB; wave wid owns chunks
  // c0=wid*2, c1=wid*2+1. lane l -> phys row c*16 + l/4, phys slot l&3.
  // phys slot s holds logical slot s ^ ((row>>1)&3); (row>>1)&3 == (l>>3)&3.
  const int rl = lane >> 2;
  const int slg = (lane & 3) ^ ((lane >> 3) & 3);
  const int c0 = wid * 2, c1 = wid * 2 + 1;
  const size_t aR0 = (size_t)imin(m0 + c0 * 16 + rl, M - 1) * lda + slg * 8;
  const size_t aR1 = (size_t)imin(m0 + c1 * 16 + rl, M - 1) * lda + slg * 8;
  const size_t bR0 = (size_t)(n0 + c0 * 16 + rl) * ldb + slg * 8;
  const size_t bR1 = (size_t)(n0 + c1 * 16 + rl) * ldb + slg * 8;

  // read-side swizzled u16 offsets: fragment row = wm+mi*16+r -> (row>>1)&3 == (r>>1)&3
  int aOff[4], bOff[4];
#pragma unroll
  for (int mi = 0; mi < 4; ++mi) aOff[mi] = (wm + mi * 16 + r) * 32 + ((g ^ ((r >> 1) & 3)) * 8);
#pragma unroll
  for (int ni = 0; ni < 4; ++ni) bOff[ni] = 4096 + (wn + ni * 16 + r) * 32 + ((g ^ ((r >> 1) & 3)) * 8);

  const int nt = kLen >> 5;  // K-steps of 32

#define STAGE(BI, T)                                        \
  do {                                                      \
    u16* bb = &sm[(BI) * 8192];                             \
    size_t kk = (size_t)(T) * 32;                           \
    glds16(A + aR0 + kk, bb + c0 * 512);                    \
    glds16(A + aR1 + kk, bb + c1 * 512);                    \
    glds16(Bt + bR0 + kk, bb + 4096 + c0 * 512);            \
    glds16(Bt + bR1 + kk, bb + 4096 + c1 * 512);            \
  } while (0)

  // prologue: tiles 0,1 -> bufs 0,1  (8 loads in flight per wave)
  STAGE(0, 0);
  STAGE(1, 1);

  for (int t = 0; t < nt - 1; ++t) {
    WAITV4;                              // my tile-t loads landed (t+1 in flight)
    __builtin_amdgcn_s_barrier();        // all waves' tile-t data published
    SCHEDB;                              // pin STAGE/ds_reads below the barrier
    if (t + 2 < nt) STAGE((t + 2) % 3, t + 2);  // overwrites tile t-1's buf (reads retired)
    const u16* bb = &sm[(t % 3) * 8192];
    bf16x8 af[4], bfr[4];
#pragma unroll
    for (int mi = 0; mi < 4; ++mi) af[mi] = *(const bf16x8*)(bb + aOff[mi]);
#pragma unroll
    for (int ni = 0; ni < 4; ++ni) bfr[ni] = *(const bf16x8*)(bb + bOff[ni]);
    __builtin_amdgcn_s_setprio(1);
#pragma unroll
    for (int mi = 0; mi < 4; ++mi)
#pragma unroll
      for (int ni = 0; ni < 4; ++ni)
        acc[mi][ni] = __builtin_amdgcn_mfma_f32_16x16x32_bf16(af[mi], bfr[ni], acc[mi][ni], 0, 0, 0);
    __builtin_amdgcn_s_setprio(0);
    SCHEDB;                              // pin this iteration's body before next WAITV
  }
  // tail iteration
  {
    WAITV0;
    __builtin_amdgcn_s_barrier();
    SCHEDB;
    const u16* bb = &sm[((nt - 1) % 3) * 8192];
    bf16x8 af[4], bfr[4];
#pragma unroll
    for (int mi = 0; mi < 4; ++mi) af[mi] = *(const bf16x8*)(bb + aOff[mi]);
#pragma unroll
    for (int ni = 0; ni < 4; ++ni) bfr[ni] = *(const bf16x8*)(bb + bOff[ni]);
#pragma unroll
    for (int mi = 0; mi < 4; ++mi)
#pragma unroll
      for (int ni = 0; ni < 4; ++ni)
        acc[mi][ni] = __builtin_amdgcn_mfma_f32_16x16x32_bf16(af[mi], bfr[ni], acc[mi][ni], 0, 0, 0);
  }
#undef STAGE

#pragma unroll
  for (int mi = 0; mi < 4; ++mi) {
#pragma unroll
    for (int ni = 0; ni < 4; ++ni) {
      const int col = n0 + wn + ni * 16 + r;
      float bv = 0.f;
      if constexpr (EPI != 4) bv = bias[col];
#pragma unroll
      for (int j = 0; j < 4; ++j) {
        const int row = m0 + wm + mi * 16 + g * 4 + j;
        if (row >= M) continue;
        const size_t off = (size_t)row * N + col;
        if constexpr (EPI == 0) {
          ((u16*)outp)[off] = f2bf(acc[mi][ni][j] + bv);
        } else if constexpr (EPI == 1) {
          ((u16*)outp)[off] = f2bf(gelu_t(acc[mi][ni][j] + bv));
        } else if constexpr (EPI == 2) {
          const int b = row / rows_per_b;
          ((float*)outp)[off] = resid[off] + modp[b * NMOD + goff + col] * (acc[mi][ni][j] + bv);
        } else if constexpr (EPI == 3) {
          ((float*)outp)[off] = resid[off] + acc[mi][ni][j] + bv;
        } else {
          ((u16*)outp)[(size_t)blockIdx.z * (size_t)goff + off] = f2bf(acc[mi][ni][j]);
        }
      }
    }
  }
}

// ---- split-K reduce for mlp2_x: out = resid + bias + p0 + p1 ----
__global__ void k_red(const u16* __restrict__ p0, const u16* __restrict__ p1,
                      const float* __restrict__ resid, const float* __restrict__ bias,
                      float* __restrict__ out) {
  size_t base = (size_t)blockIdx.x * DD;
#pragma unroll
  for (int i = 0; i < 6; ++i) {
    int j = threadIdx.x + 256 * i;
    out[base + j] = resid[base + j] + bias[j] + bf2f(p0[base + j]) + bf2f(p1[base + j]);
  }
}

// ---- scatter qkv GEMM output into q,k (b,h,t,d) bf16 ----
__global__ void k_qk(const u16* __restrict__ qkvx, const u16* __restrict__ qkvc,
                     u16* __restrict__ q, u16* __restrict__ k) {
  int idx = blockIdx.x * 256 + threadIdx.x;
  if (idx >= NT * 64) return;
  int t = idx >> 6, d = idx & 63;
  int h = blockIdx.y, b = blockIdx.z;
  const u16* src = (t < NX) ? qkvx + (size_t)(b * NX + t) * NQKV
                            : qkvc + (size_t)(b * NC + t - NX) * NQKV;
  size_t o = ((size_t)(b * HH + h) * NT + t) * 64 + d;
  q[o] = src[h * 64 + d];
  k[o] = src[DD + h * 64 + d];
}

// ---- V transpose: qkv v-cols -> vt (b,h,d,t) bf16, t-stride NTP ----
__global__ void k_vt(const u16* __restrict__ qkvx, const u16* __restrict__ qkvc,
                     u16* __restrict__ vt) {
  __shared__ u16 tile[64][65];
  int t0 = blockIdx.x * 64;
  int h = blockIdx.y, b = blockIdx.z;
  int tx = threadIdx.x & 63, ty = threadIdx.x >> 6;
#pragma unroll
  for (int j = 0; j < 16; ++j) {
    int tt = ty * 16 + j;
    int t = t0 + tt;
    if (t < NT) {
      const u16* src = (t < NX) ? qkvx + (size_t)(b * NX + t) * NQKV
                                : qkvc + (size_t)(b * NC + t - NX) * NQKV;
      tile[tt][tx] = src[2 * DD + h * 64 + tx];
    }
  }
  __syncthreads();
  size_t base = (size_t)(b * HH + h) * 64 * NTP;
#pragma unroll
  for (int j = 0; j < 16; ++j) {
    int dd = ty * 16 + j;
    int t = t0 + tx;
    if (t < NT) vt[base + (size_t)dd * NTP + t] = tile[tx][dd];
  }
}

// ---- flash attention: QBLK=64 (4 waves x 16 rows), KBLK=64, HD=64 ----
// Swapped QK^T (S^T = mfma(K,Q)): lane owns q-row (lane&15), 16 in-lane t.
// In-register softmax (2 shfl max + 2 shfl sum), packed b64 P-writes,
// next-tile K/V register prefetch under compute.
__global__ LB256 void k_attn(const u16* __restrict__ q, const u16* __restrict__ kk,
                             const u16* __restrict__ vt, u16* __restrict__ ox,
                             u16* __restrict__ oc) {
  __shared__ __align__(16) u16 Ks[64][72];
  __shared__ __align__(16) u16 Vs[64][72];
  __shared__ __align__(16) u16 Ps[4][16][72];

  const int lane = threadIdx.x & 63, wid = threadIdx.x >> 6;
  const int g = lane >> 4, r = lane & 15;
  const int q0 = blockIdx.x * 64;
  const int h = blockIdx.y, b = blockIdx.z;
  const size_t bh = (size_t)b * HH + h;
  const u16* qp = q + bh * (NT * 64);
  const u16* kp = kk + bh * (NT * 64);
  const u16* vp = vt + bh * (64 * NTP);

  // Q rows, scale 1/8 folded in at load
  const int qrow = imin(q0 + wid * 16 + r, NT - 1);
  u16x8 qr0 = *(const u16x8*)(qp + (size_t)qrow * 64 + g * 8);
  u16x8 qr1 = *(const u16x8*)(qp + (size_t)qrow * 64 + 32 + g * 8);
  bf16x8 qa0, qa1;
#pragma unroll
  for (int e = 0; e < 8; ++e) {
    qa0[e] = (short)f2bf(bf2f(qr0[e]) * 0.125f);
    qa1[e] = (short)f2bf(bf2f(qr1[e]) * 0.125f);
  }

  f32x4 oacc[4];
#pragma unroll
  for (int i = 0; i < 4; ++i) oacc[i] = fzero4();
  float mrow = -1e30f, lrow = 0.f;

  // staging lanes: thread covers chunks p=0,1 of the 64x64 tile
  int trA[2], ccA[2];
#pragma unroll
  for (int p = 0; p < 2; ++p) {
    int chunk = p * 256 + threadIdx.x;
    trA[p] = chunk >> 3;
    ccA[p] = (chunk & 7) * 8;
  }

  u16x8 kreg[2], vreg[2];
#define LOADKV(T0)                                                         \
  do {                                                                     \
    _Pragma("unroll")                                                      \
    for (int p = 0; p < 2; ++p) {                                          \
      int tsrc = imin((T0) + trA[p], NT - 1);                              \
      kreg[p] = *(const u16x8*)(kp + (size_t)tsrc * 64 + ccA[p]);          \
      int tcol = (T0) + ccA[p];                                            \
      if (tcol + 8 <= NT) {                                                \
        vreg[p] = *(const u16x8*)(vp + (size_t)trA[p] * NTP + tcol);       \
      } else {                                                             \
        _Pragma("unroll")                                                  \
        for (int e = 0; e < 8; ++e)                                        \
          vreg[p][e] = vp[(size_t)trA[p] * NTP + imin(tcol + e, NT - 1)];  \
      }                                                                    \
    }                                                                      \
  } while (0)

  LOADKV(0);

  for (int t0 = 0; t0 < NT; t0 += 64) {
    if (t0) __syncthreads();            // prior tile's LDS reads retired
#pragma unroll
    for (int p = 0; p < 2; ++p) {
      *(u16x8*)&Ks[trA[p]][ccA[p]] = kreg[p];
      *(u16x8*)&Vs[trA[p]][ccA[p]] = vreg[p];
    }
    __syncthreads();                    // tile published
    if (t0 + 64 < NT) LOADKV(t0 + 64);  // prefetch next tile; latency hides under compute

    // S^T = K Q^T (swapped operands; same fragment reads as before)
    f32x4 s[4];
#pragma unroll
    for (int ni = 0; ni < 4; ++ni) {
      s[ni] = fzero4();
      s[ni] = __builtin_amdgcn_mfma_f32_16x16x32_bf16(*(const bf16x8*)&Ks[ni * 16 + r][g * 8], qa0, s[ni], 0, 0, 0);
      s[ni] = __builtin_amdgcn_mfma_f32_16x16x32_bf16(*(const bf16x8*)&Ks[ni * 16 + r][32 + g * 8], qa1, s[ni], 0, 0, 0);
    }

    // lane (g,r) holds S[t = t0 + ni*16 + g*4 + j][q = q-row r]
    float pv[4][4];
    float pm = -1e30f;
#pragma unroll
    for (int ni = 0; ni < 4; ++ni)
#pragma unroll
      for (int j = 0; j < 4; ++j) {
        int t = t0 + ni * 16 + g * 4 + j;
        float sv = (t < NT) ? s[ni][j] : -1e30f;
        pv[ni][j] = sv;
        pm = fmaxf(pm, sv);
      }
    pm = fmaxf(pm, __shfl_xor(pm, 16));
    pm = fmaxf(pm, __shfl_xor(pm, 32));

    float mn = fmaxf(mrow, pm);
    float alpha = __expf(mrow - mn);
    mrow = mn;
    float rs = 0.f;
#pragma unroll
    for (int ni = 0; ni < 4; ++ni)
#pragma unroll
      for (int j = 0; j < 4; ++j) {
        float p = __expf(pv[ni][j] - mn);
        pv[ni][j] = p;
        rs += p;
      }
    rs += __shfl_xor(rs, 16);
    rs += __shfl_xor(rs, 32);
    lrow = lrow * alpha + rs;

    // rescale O: alpha for q = g*4+j lives at lane (g*4+j) (its r == q, g'=0 copy)
#pragma unroll
    for (int j = 0; j < 4; ++j) {
      float aj = __shfl(alpha, g * 4 + j);
#pragma unroll
      for (int ni = 0; ni < 4; ++ni) oacc[ni][j] *= aj;
    }

    // pack P -> bf16 pairs, one b64 write per ni (row = own q-row r)
#pragma unroll
    for (int ni = 0; ni < 4; ++ni) {
      u32x2 w;
      w[0] = (u32)f2bf(pv[ni][0]) | ((u32)f2bf(pv[ni][1]) << 16);
      w[1] = (u32)f2bf(pv[ni][2]) | ((u32)f2bf(pv[ni][3]) << 16);
      *(u32x2*)&Ps[wid][r][ni * 16 + g * 4] = w;
    }

    bf16x8 pa0 = *(const bf16x8*)&Ps[wid][r][g * 8];
    bf16x8 pa1 = *(const bf16x8*)&Ps[wid][r][32 + g * 8];
#pragma unroll
    for (int ni = 0; ni < 4; ++ni) {
      oacc[ni] = __builtin_amdgcn_mfma_f32_16x16x32_bf16(pa0, *(const bf16x8*)&Vs[ni * 16 + r][g * 8], oacc[ni], 0, 0, 0);
      oacc[ni] = __builtin_amdgcn_mfma_f32_16x16x32_bf16(pa1, *(const bf16x8*)&Vs[ni * 16 + r][32 + g * 8], oacc[ni], 0, 0, 0);
    }
  }
#undef LOADKV

  // final 1/l for q = g*4+j
  float linv[4];
#pragma unroll
  for (int j = 0; j < 4; ++j) linv[j] = 1.f / __shfl(lrow, g * 4 + j);

#pragma unroll
  for (int ni = 0; ni < 4; ++ni)
#pragma unroll
    for (int j = 0; j < 4; ++j) {
      int tq = q0 + wid * 16 + g * 4 + j;
      if (tq >= NT) continue;
      float val = oacc[ni][j] * linv[j];
      int col = h * 64 + ni * 16 + r;
      if (tq < NX)
        ox[(size_t)(b * NX + tq) * DD + col] = f2bf(val);
      else
        oc[(size_t)(b * NC + tq - NX) * DD + col] = f2bf(val);
    }
}

extern "C" void kernel_launch(void* const* d_in, const int* in_sizes, int n_in,
                              void* d_out, int out_size, void* d_ws, size_t ws_size,
                              hipStream_t stream) {
  const float* x = (const float*)d_in[0];
  const float* c = (const float*)d_in[1];
  const float* vec = (const float*)d_in[2];
  const float* w_mod = (const float*)d_in[3];
  const float* b_mod = (const float*)d_in[4];
  const float* w_qkv_x = (const float*)d_in[5];
  const float* b_qkv_x = (const float*)d_in[6];
  const float* w_qkv_c = (const float*)d_in[7];
  const float* b_qkv_c = (const float*)d_in[8];
  const float* w_proj_x = (const float*)d_in[9];
  const float* b_proj_x = (const float*)d_in[10];
  const float* w_proj_c = (const float*)d_in[11];
  const float* b_proj_c = (const float*)d_in[12];
  const float* w1_x = (const float*)d_in[13];
  const float* b1_x = (const float*)d_in[14];
  const float* w2_x = (const float*)d_in[15];
  const float* b2_x = (const float*)d_in[16];
  const float* w1_c = (const float*)d_in[17];
  const float* b1_c = (const float*)d_in[18];
  const float* w2_c = (const float*)d_in[19];
  const float* b2_c = (const float*)d_in[20];

  if (ws_size < 229195776ull) return;  // workspace layout below needs this much

  char* ws = (char*)d_ws;
  // persistent: bf16-transposed weights + mod
  u16* wt_qkv_x = (u16*)(ws + 0);
  u16* wt_qkv_c = (u16*)(ws + 14155776);
  u16* wt_proj_x = (u16*)(ws + 28311552);
  u16* wt_proj_c = (u16*)(ws + 33030144);
  u16* wt_w1_x = (u16*)(ws + 37748736);
  u16* wt_w1_c = (u16*)(ws + 56623104);
  u16* wt_w2_x = (u16*)(ws + 75497472);
  u16* wt_w2_c = (u16*)(ws + 94371840);
  float* modf = (float*)(ws + 113246208);
  char* S = ws + 113393664;
  // slot 1 (14,475,264 B): x_n/c_n -> o_x/o_c -> xln/cln -> pb0 (mlp2 partial z=0)
  u16* xn = (u16*)(S);
  u16* cn = (u16*)(S + 12582912);
  // slot 2 (43,425,792 B): qkv_x_out/qkv_c_out -> x2/c2 (f32)
  u16* qkvx = (u16*)(S + 14475264);
  u16* qkvc = (u16*)(S + 52224000);
  float* x2 = (float*)(S + 14475264);   // 25,165,824 B, ends S+39,641,088
  float* c2 = (float*)(S + 39641088);   //  3,784,704 B, ends S+43,425,792
  u16* pb0 = (u16*)(S);                 // 12,582,912 B (xn/cn dead after mlp1 reads)
  u16* pb1 = (u16*)(S + 43425792);      // 12,582,912 B (qkv outputs dead, after c2)
  // partial stride pb0 -> pb1 in u16 elements:
  const int PSTRIDE = 43425792 / 2;     // 21,712,896
  // slot 3 (57,901,056 B): q/k/vt -> h_x/h_c ; head also used as k_mod partials
  u16* qb = (u16*)(S + 57901056);
  u16* kb = (u16*)(S + 72376320);
  u16* vtb = (u16*)(S + 86851584);
  u16* hx = (u16*)(S + 57901056);
  u16* hc = (u16*)(S + 108232704);
  float* modpart = (float*)(S + 57901056);  // 884736 B, dead before q/k/vt written

  // 1) weights -> bf16 transposed
  k_transpose<<<dim3(NQKV / 32, DD / 32), 256, 0, stream>>>(w_qkv_x, wt_qkv_x, DD, NQKV);
  k_transpose<<<dim3(NQKV / 32, DD / 32), 256, 0, stream>>>(w_qkv_c, wt_qkv_c, DD, NQKV);
  k_transpose<<<dim3(DD / 32, DD / 32), 256, 0, stream>>>(w_proj_x, wt_proj_x, DD, DD);
  k_transpose<<<dim3(DD / 32, DD / 32), 256, 0, stream>>>(w_proj_c, wt_proj_c, DD, DD);
  k_transpose<<<dim3(MHD / 32, DD / 32), 256, 0, stream>>>(w1_x, wt_w1_x, DD, MHD);
  k_transpose<<<dim3(MHD / 32, DD / 32), 256, 0, stream>>>(w1_c, wt_w1_c, DD, MHD);
  k_transpose<<<dim3(DD / 32, MHD / 32), 256, 0, stream>>>(w2_x, wt_w2_x, MHD, DD);
  k_transpose<<<dim3(DD / 32, MHD / 32), 256, 0, stream>>>(w2_c, wt_w2_c, MHD, DD);

  // 2) modulation vector (split-K, deterministic two-stage)
  k_mod_part<<<dim3(NMOD / 256, KSPL), 256, 0, stream>>>(vec, w_mod, modpart);
  k_mod_red<<<dim3(NMOD / 256), 256, 0, stream>>>(modpart, b_mod, modf);

  // 3) modulated LN -> bf16
  k_ln<<<dim3(BB * NX), 256, 0, stream>>>(x, xn, modf, 0, DD, NX);
  k_ln<<<dim3(BB * NC), 256, 0, stream>>>(c, cn, modf, 3 * DD, 4 * DD, NC);

  // 4) QKV GEMMs (x-stream on 256x256 2-blocks/CU kernel)
  k_gemm256<0><<<dim3(NQKV / 256, (BB * NX) / 256), 512, 0, stream>>>(xn, wt_qkv_x, b_qkv_x, NQKV, DD, DD, DD, qkvx);
  k_gemm<0><<<dim3(NQKV / 128, 5), 256, 0, stream>>>(cn, wt_qkv_c, b_qkv_c, BB * NC, NQKV, DD, DD, DD, 0, qkvc, nullptr, nullptr, 0, 1);

  // 5) reshape to q/k (b,h,t,d) and vt (b,h,d,t)
  k_qk<<<dim3((NT * 64 + 255) / 256, HH, BB), 256, 0, stream>>>(qkvx, qkvc, qb, kb);
  k_vt<<<dim3((NT + 63) / 64, HH, BB), 256, 0, stream>>>(qkvx, qkvc, vtb);

  // 6) flash attention -> o (written into slot 1)
  k_attn<<<dim3((NT + 63) / 64, HH, BB), 256, 0, stream>>>(qb, kb, vtb, xn, cn);

  // 7) output projections with gated residual -> x2/c2 f32
  k_gemm<2><<<dim3(DD / 128, 32), 256, 0, stream>>>(xn, wt_proj_x, b_proj_x, BB * NX, DD, DD, DD, DD, 0, x2, x, modf, 2 * DD, NX);
  k_gemm<2><<<dim3(DD / 128, 5), 256, 0, stream>>>(cn, wt_proj_c, b_proj_c, BB * NC, DD, DD, DD, DD, 0, c2, c, modf, 5 * DD, NC);

  // 8) plain LN -> bf16
  k_ln<<<dim3(BB * NX), 256, 0, stream>>>(x2, xn, nullptr, 0, 0, NX);
  k_ln<<<dim3(BB * NC), 256, 0, stream>>>(c2, cn, nullptr, 0, 0, NC);

  // 9) MLP (mlp1_x on 256x256 2-blocks/CU kernel)
  k_gemm256<1><<<dim3(MHD / 256, (BB * NX) / 256), 512, 0, stream>>>(xn, wt_w1_x, b1_x, MHD, DD, DD, DD, hx);
  k_gemm<1><<<dim3(MHD / 128, 5), 256, 0, stream>>>(cn, wt_w1_c, b1_c, BB * NC, MHD, DD, DD, DD, 0, hc, nullptr, nullptr, 0, 1);

  float* outx = (float*)d_out;
  float* outc = outx + (size_t)BB * NX * DD;
  // mlp2_x: concurrent split-K (z=0: K[0,3072), z=1: K[3072,6144)) -> bf16
  // partials at pb0 / pb0 + PSTRIDE (== pb1, disjoint from live x2/c2) -> reduce
  k_gemm<4><<<dim3(DD / 128, 32, 2), 256, 0, stream>>>(hx, wt_w2_x, b2_x, BB * NX, DD, MHD, MHD, MHD / 2, MHD / 2, pb0, nullptr, nullptr, PSTRIDE, NX);
  k_red<<<dim3(BB * NX), 256, 0, stream>>>(pb0, pb1, x2, b2_x, outx);
  k_gemm<3><<<dim3(DD / 128, 5), 256, 0, stream>>>(hc, wt_w2_c, b2_c, BB * NC, DD, MHD, MHD, MHD, 0, outc, c2, nullptr, 0, NC);
}

// Round 9
// 857.280 us; speedup vs baseline: 2.9005x; 2.9005x over previous
//
#include <hip/hip_runtime.h>
#include <stdint.h>

typedef unsigned short u16;
typedef unsigned int u32;
typedef __attribute__((ext_vector_type(8))) short bf16x8;
typedef __attribute__((ext_vector_type(8))) unsigned short u16x8;
typedef __attribute__((ext_vector_type(2))) unsigned int u32x2;
typedef __attribute__((ext_vector_type(4))) float f32x4;

#define LB256 __launch_bounds__(256, 2)

// ---- problem dims ----
#define BB 4
#define NX 1024
#define NC 154
#define NT 1178
#define NTP 1184   // padded t stride for V^T (16B-aligned rows)
#define DD 1536
#define HH 24
#define MHD 6144
#define NQKV 4608
#define NMOD 9216
#define KSPL 6

__device__ __forceinline__ int imin(int a, int b) { return a < b ? a : b; }

__device__ __forceinline__ u16 f2bf(float f) {
  u32 u = __float_as_uint(f);
  u32 r = (u + 0x7fffu + ((u >> 16) & 1u)) >> 16;
  return (u16)r;
}

__device__ __forceinline__ float bf2f(u16 v) {
  u32 u = ((u32)v) << 16;
  return __uint_as_float(u);
}

__device__ __forceinline__ float gelu_t(float x) {
  float x2 = x * x;
  float t = tanhf(0.7978845608028654f * x * (1.f + 0.044715f * x2));
  return 0.5f * x * (1.f + t);
}

__device__ __forceinline__ f32x4 fzero4() {
  f32x4 z; z[0] = 0.f; z[1] = 0.f; z[2] = 0.f; z[3] = 0.f; return z;
}

// async global->LDS, 16B per lane; LDS dest = wave-uniform base + lane*16
__device__ __forceinline__ void glds16(const u16* g, u16* l) {
  __builtin_amdgcn_global_load_lds(
      (const __attribute__((address_space(1))) void*)g,
      (__attribute__((address_space(3))) void*)l, 16, 0, 0);
}

#define WAITV4 asm volatile("s_waitcnt vmcnt(4)" ::: "memory")
#define WAITV0 asm volatile("s_waitcnt vmcnt(0)" ::: "memory")
#define SCHEDB __builtin_amdgcn_sched_barrier(0)

// ---- weight transpose + f32->bf16: W[K][N] -> Wt[N][K] ----
__global__ void k_transpose(const float* __restrict__ W, u16* __restrict__ Wt, int K, int N) {
  __shared__ float tile[32][33];
  int n0 = blockIdx.x * 32, k0 = blockIdx.y * 32;
  int tx = threadIdx.x & 31, ty = threadIdx.x >> 5;  // 32 x 8
#pragma unroll
  for (int j = 0; j < 32; j += 8)
    tile[ty + j][tx] = W[(size_t)(k0 + ty + j) * N + n0 + tx];
  __syncthreads();
#pragma unroll
  for (int j = 0; j < 32; j += 8)
    Wt[(size_t)(n0 + ty + j) * K + k0 + tx] = f2bf(tile[tx][ty + j]);
}

// ---- mod = silu(vec) @ w_mod + b_mod : split-K partials (deterministic) ----
__global__ void k_mod_part(const float* __restrict__ vec, const float* __restrict__ w_mod,
                           float* __restrict__ part) {
  __shared__ float sv[BB][256];
  int n = blockIdx.x * 256 + threadIdx.x;
  int kb = blockIdx.y;
  int k0 = kb * 256;
  for (int i = threadIdx.x; i < BB * 256; i += 256) {
    int b = i >> 8, kk = i & 255;
    float v = vec[b * DD + k0 + kk];
    sv[b][kk] = v / (1.f + __expf(-v));
  }
  __syncthreads();
  float a0 = 0.f, a1 = 0.f, a2 = 0.f, a3 = 0.f;
  for (int k = 0; k < 256; ++k) {
    float w = w_mod[(size_t)(k0 + k) * NMOD + n];
    a0 = fmaf(sv[0][k], w, a0);
    a1 = fmaf(sv[1][k], w, a1);
    a2 = fmaf(sv[2][k], w, a2);
    a3 = fmaf(sv[3][k], w, a3);
  }
  part[((size_t)kb * BB + 0) * NMOD + n] = a0;
  part[((size_t)kb * BB + 1) * NMOD + n] = a1;
  part[((size_t)kb * BB + 2) * NMOD + n] = a2;
  part[((size_t)kb * BB + 3) * NMOD + n] = a3;
}

__global__ void k_mod_red(const float* __restrict__ part, const float* __restrict__ b_mod,
                          float* __restrict__ mod) {
  int n = blockIdx.x * 256 + threadIdx.x;
  float bb = b_mod[n];
#pragma unroll
  for (int b = 0; b < BB; ++b) {
    float s = bb;
#pragma unroll
    for (int kb = 0; kb < KSPL; ++kb) s += part[((size_t)kb * BB + b) * NMOD + n];
    mod[b * NMOD + n] = s;
  }
}

// ---- LayerNorm (optionally modulated) f32 -> bf16 ----
__global__ LB256 void k_ln(const float* __restrict__ in, u16* __restrict__ out,
                           const float* __restrict__ modp, int sh_off, int sc_off,
                           int rows_per_b) {
  int row = blockIdx.x;
  int b = row / rows_per_b;
  const float* xr = in + (size_t)row * DD;
  float v[6];
  float s = 0.f, s2 = 0.f;
#pragma unroll
  for (int i = 0; i < 6; ++i) {
    float t = xr[threadIdx.x + 256 * i];
    v[i] = t; s += t; s2 += t * t;
  }
#pragma unroll
  for (int m = 32; m >= 1; m >>= 1) {
    s += __shfl_xor(s, m);
    s2 += __shfl_xor(s2, m);
  }
  __shared__ float red[8];
  int wid = threadIdx.x >> 6;
  if ((threadIdx.x & 63) == 0) { red[wid] = s; red[4 + wid] = s2; }
  __syncthreads();
  s = red[0] + red[1] + red[2] + red[3];
  s2 = red[4] + red[5] + red[6] + red[7];
  float mean = s * (1.f / (float)DD);
  float var = s2 * (1.f / (float)DD) - mean * mean;
  float rstd = rsqrtf(var + 1e-6f);
#pragma unroll
  for (int i = 0; i < 6; ++i) {
    int d = threadIdx.x + 256 * i;
    float y = (v[i] - mean) * rstd;
    if (modp) y = y * (1.f + modp[b * NMOD + sc_off + d]) + modp[b * NMOD + sh_off + d];
    out[(size_t)row * DD + d] = f2bf(y);
  }
}

// ---- pipelined bf16 MFMA GEMM: C = A(MxK) @ Bt(NxK)^T (+bias), 128x128x32 tile
// 3-buffer LDS, counted vmcnt(4), single raw barrier per K-step, XOR-swizzled LDS.
// EPI: 0 bias->bf16 | 1 gelu(bias+acc)->bf16 | 2 resid+g*(acc+bias)->f32 |
//      3 resid+acc+bias->f32 | 4 acc->bf16 partial at outp + z*goff (split-K)
template <int EPI>
__global__ LB256 void k_gemm(const u16* __restrict__ A, const u16* __restrict__ Bt,
                             const float* __restrict__ bias, int M, int N,
                             int lda, int ldb, int kLen, int kzOff,
                             void* __restrict__ outp, const float* __restrict__ resid,
                             const float* __restrict__ modp, int goff, int rows_per_b) {
  __shared__ __align__(16) u16 sm[3 * 8192];  // 3 x (A 4096 + B 4096) u16 = 48 KB
  const int tid = threadIdx.x;
  const int lane = tid & 63;
  const int g = lane >> 4, r = lane & 15;
  const int wid = tid >> 6;

  // bijective XCD-aware tile remap (m204)
  const int gx = gridDim.x;
  const int nwg = gx * gridDim.y;
  int wg = blockIdx.y * gx + blockIdx.x;
  {
    int q = nwg >> 3, rr = nwg & 7;
    int xcd = wg & 7, sl = wg >> 3;
    wg = (xcd < rr ? xcd * (q + 1) : rr * (q + 1) + (xcd - rr) * q) + sl;
  }
  const int m0 = (wg / gx) * 128, n0 = (wg % gx) * 128;
  const int wm = (wid >> 1) * 64, wn = (wid & 1) * 64;

  A += (size_t)blockIdx.z * kzOff;
  Bt += (size_t)blockIdx.z * kzOff;

  f32x4 acc[4][4];
#pragma unroll
  for (int i = 0; i < 4; ++i)
#pragma unroll
    for (int j = 0; j < 4; ++j) acc[i][j] = fzero4();

  // staging geometry: tile (A or B) = 8 chunks of 1KB; wave wid owns chunks
  // c0=wid*2, c1=wid*2+1. lane l -> phys row c*16 + l/4, phys slot l&3.
  // phys slot s holds logical slot s ^ ((row>>1)&3); (row>>1)&3 == (l>>3)&3.
  const int rl = lane >> 2;
  const int slg = (lane & 3) ^ ((lane >> 3) & 3);
  const int c0 = wid * 2, c1 = wid * 2 + 1;
  const size_t aR0 = (size_t)imin(m0 + c0 * 16 + rl, M - 1) * lda + slg * 8;
  const size_t aR1 = (size_t)imin(m0 + c1 * 16 + rl, M - 1) * lda + slg * 8;
  const size_t bR0 = (size_t)(n0 + c0 * 16 + rl) * ldb + slg * 8;
  const size_t bR1 = (size_t)(n0 + c1 * 16 + rl) * ldb + slg * 8;

  // read-side swizzled u16 offsets: fragment row = wm+mi*16+r -> (row>>1)&3 == (r>>1)&3
  int aOff[4], bOff[4];
#pragma unroll
  for (int mi = 0; mi < 4; ++mi) aOff[mi] = (wm + mi * 16 + r) * 32 + ((g ^ ((r >> 1) & 3)) * 8);
#pragma unroll
  for (int ni = 0; ni < 4; ++ni) bOff[ni] = 4096 + (wn + ni * 16 + r) * 32 + ((g ^ ((r >> 1) & 3)) * 8);

  const int nt = kLen >> 5;  // K-steps of 32

#define STAGE(BI, T)                                        \
  do {                                                      \
    u16* bb = &sm[(BI) * 8192];                             \
    size_t kk = (size_t)(T) * 32;                           \
    glds16(A + aR0 + kk, bb + c0 * 512);                    \
    glds16(A + aR1 + kk, bb + c1 * 512);                    \
    glds16(Bt + bR0 + kk, bb + 4096 + c0 * 512);            \
    glds16(Bt + bR1 + kk, bb + 4096 + c1 * 512);            \
  } while (0)

  // prologue: tiles 0,1 -> bufs 0,1  (8 loads in flight per wave)
  STAGE(0, 0);
  STAGE(1, 1);

  for (int t = 0; t < nt - 1; ++t) {
    WAITV4;                              // my tile-t loads landed (t+1 in flight)
    __builtin_amdgcn_s_barrier();        // all waves' tile-t data published
    SCHEDB;                              // pin STAGE/ds_reads below the barrier
    if (t + 2 < nt) STAGE((t + 2) % 3, t + 2);  // overwrites tile t-1's buf (reads retired)
    const u16* bb = &sm[(t % 3) * 8192];
    bf16x8 af[4], bfr[4];
#pragma unroll
    for (int mi = 0; mi < 4; ++mi) af[mi] = *(const bf16x8*)(bb + aOff[mi]);
#pragma unroll
    for (int ni = 0; ni < 4; ++ni) bfr[ni] = *(const bf16x8*)(bb + bOff[ni]);
    __builtin_amdgcn_s_setprio(1);
#pragma unroll
    for (int mi = 0; mi < 4; ++mi)
#pragma unroll
      for (int ni = 0; ni < 4; ++ni)
        acc[mi][ni] = __builtin_amdgcn_mfma_f32_16x16x32_bf16(af[mi], bfr[ni], acc[mi][ni], 0, 0, 0);
    __builtin_amdgcn_s_setprio(0);
    SCHEDB;                              // pin this iteration's body before next WAITV
  }
  // tail iteration
  {
    WAITV0;
    __builtin_amdgcn_s_barrier();
    SCHEDB;
    const u16* bb = &sm[((nt - 1) % 3) * 8192];
    bf16x8 af[4], bfr[4];
#pragma unroll
    for (int mi = 0; mi < 4; ++mi) af[mi] = *(const bf16x8*)(bb + aOff[mi]);
#pragma unroll
    for (int ni = 0; ni < 4; ++ni) bfr[ni] = *(const bf16x8*)(bb + bOff[ni]);
#pragma unroll
    for (int mi = 0; mi < 4; ++mi)
#pragma unroll
      for (int ni = 0; ni < 4; ++ni)
        acc[mi][ni] = __builtin_amdgcn_mfma_f32_16x16x32_bf16(af[mi], bfr[ni], acc[mi][ni], 0, 0, 0);
  }
#undef STAGE

#pragma unroll
  for (int mi = 0; mi < 4; ++mi) {
#pragma unroll
    for (int ni = 0; ni < 4; ++ni) {
      const int col = n0 + wn + ni * 16 + r;
      float bv = 0.f;
      if constexpr (EPI != 4) bv = bias[col];
#pragma unroll
      for (int j = 0; j < 4; ++j) {
        const int row = m0 + wm + mi * 16 + g * 4 + j;
        if (row >= M) continue;
        const size_t off = (size_t)row * N + col;
        if constexpr (EPI == 0) {
          ((u16*)outp)[off] = f2bf(acc[mi][ni][j] + bv);
        } else if constexpr (EPI == 1) {
          ((u16*)outp)[off] = f2bf(gelu_t(acc[mi][ni][j] + bv));
        } else if constexpr (EPI == 2) {
          const int b = row / rows_per_b;
          ((float*)outp)[off] = resid[off] + modp[b * NMOD + goff + col] * (acc[mi][ni][j] + bv);
        } else if constexpr (EPI == 3) {
          ((float*)outp)[off] = resid[off] + acc[mi][ni][j] + bv;
        } else {
          ((u16*)outp)[(size_t)blockIdx.z * (size_t)goff + off] = f2bf(acc[mi][ni][j]);
        }
      }
    }
  }
}

// ---- split-K reduce for mlp2_x: out = resid + bias + p0 + p1 ----
__global__ void k_red(const u16* __restrict__ p0, const u16* __restrict__ p1,
                      const float* __restrict__ resid, const float* __restrict__ bias,
                      float* __restrict__ out) {
  size_t base = (size_t)blockIdx.x * DD;
#pragma unroll
  for (int i = 0; i < 6; ++i) {
    int j = threadIdx.x + 256 * i;
    out[base + j] = resid[base + j] + bias[j] + bf2f(p0[base + j]) + bf2f(p1[base + j]);
  }
}

// ---- scatter qkv GEMM output into q,k (b,h,t,d) bf16 ----
__global__ void k_qk(const u16* __restrict__ qkvx, const u16* __restrict__ qkvc,
                     u16* __restrict__ q, u16* __restrict__ k) {
  int idx = blockIdx.x * 256 + threadIdx.x;
  if (idx >= NT * 64) return;
  int t = idx >> 6, d = idx & 63;
  int h = blockIdx.y, b = blockIdx.z;
  const u16* src = (t < NX) ? qkvx + (size_t)(b * NX + t) * NQKV
                            : qkvc + (size_t)(b * NC + t - NX) * NQKV;
  size_t o = ((size_t)(b * HH + h) * NT + t) * 64 + d;
  q[o] = src[h * 64 + d];
  k[o] = src[DD + h * 64 + d];
}

// ---- V transpose: qkv v-cols -> vt (b,h,d,t) bf16, t-stride NTP ----
__global__ void k_vt(const u16* __restrict__ qkvx, const u16* __restrict__ qkvc,
                     u16* __restrict__ vt) {
  __shared__ u16 tile[64][65];
  int t0 = blockIdx.x * 64;
  int h = blockIdx.y, b = blockIdx.z;
  int tx = threadIdx.x & 63, ty = threadIdx.x >> 6;
#pragma unroll
  for (int j = 0; j < 16; ++j) {
    int tt = ty * 16 + j;
    int t = t0 + tt;
    if (t < NT) {
      const u16* src = (t < NX) ? qkvx + (size_t)(b * NX + t) * NQKV
                                : qkvc + (size_t)(b * NC + t - NX) * NQKV;
      tile[tt][tx] = src[2 * DD + h * 64 + tx];
    }
  }
  __syncthreads();
  size_t base = (size_t)(b * HH + h) * 64 * NTP;
#pragma unroll
  for (int j = 0; j < 16; ++j) {
    int dd = ty * 16 + j;
    int t = t0 + tx;
    if (t < NT) vt[base + (size_t)dd * NTP + t] = tile[tx][dd];
  }
}

// ---- flash attention: QBLK=128 (8 waves x 16 rows), KBLK=64, HD=64 ----
// Swapped QK^T (S^T = mfma(K,Q)): lane owns q-row (lane&15), 16 in-lane t.
// In-register softmax (2 shfl max + 2 shfl sum), packed b64 P-writes,
// next-tile K/V register prefetch under compute. 512 threads: each thread
// stages exactly one 16B K-segment and one 16B V-segment per tile.
__global__ __launch_bounds__(512, 2) void k_attn(
    const u16* __restrict__ q, const u16* __restrict__ kk,
    const u16* __restrict__ vt, u16* __restrict__ ox, u16* __restrict__ oc) {
  __shared__ __align__(16) u16 Ks[64][72];
  __shared__ __align__(16) u16 Vs[64][72];
  __shared__ __align__(16) u16 Ps[8][16][72];

  const int lane = threadIdx.x & 63, wid = threadIdx.x >> 6;  // wid 0..7
  const int g = lane >> 4, r = lane & 15;
  const int q0 = blockIdx.x * 128;
  const int h = blockIdx.y, b = blockIdx.z;
  const size_t bh = (size_t)b * HH + h;
  const u16* qp = q + bh * (NT * 64);
  const u16* kp = kk + bh * (NT * 64);
  const u16* vp = vt + bh * (64 * NTP);

  // Q rows, scale 1/8 folded in at load
  const int qrow = imin(q0 + wid * 16 + r, NT - 1);
  u16x8 qr0 = *(const u16x8*)(qp + (size_t)qrow * 64 + g * 8);
  u16x8 qr1 = *(const u16x8*)(qp + (size_t)qrow * 64 + 32 + g * 8);
  bf16x8 qa0, qa1;
#pragma unroll
  for (int e = 0; e < 8; ++e) {
    qa0[e] = (short)f2bf(bf2f(qr0[e]) * 0.125f);
    qa1[e] = (short)f2bf(bf2f(qr1[e]) * 0.125f);
  }

  f32x4 oacc[4];
#pragma unroll
  for (int i = 0; i < 4; ++i) oacc[i] = fzero4();
  float mrow = -1e30f, lrow = 0.f;

  // staging: thread owns 16B unit (trA, ccA) of the 64x64 tile
  const int trA = threadIdx.x >> 3;
  const int ccA = (threadIdx.x & 7) * 8;

  u16x8 kreg, vreg;
#define LOADKV(T0)                                                     \
  do {                                                                 \
    int tsrc = imin((T0) + trA, NT - 1);                               \
    kreg = *(const u16x8*)(kp + (size_t)tsrc * 64 + ccA);              \
    int tcol = (T0) + ccA;                                             \
    if (tcol + 8 <= NT) {                                              \
      vreg = *(const u16x8*)(vp + (size_t)trA * NTP + tcol);           \
    } else {                                                           \
      _Pragma("unroll")                                                \
      for (int e = 0; e < 8; ++e)                                      \
        vreg[e] = vp[(size_t)trA * NTP + imin(tcol + e, NT - 1)];      \
    }                                                                  \
  } while (0)

  LOADKV(0);

  for (int t0 = 0; t0 < NT; t0 += 64) {
    if (t0) __syncthreads();            // prior tile's LDS reads retired
    *(u16x8*)&Ks[trA][ccA] = kreg;
    *(u16x8*)&Vs[trA][ccA] = vreg;
    __syncthreads();                    // tile published
    if (t0 + 64 < NT) LOADKV(t0 + 64);  // prefetch next tile; latency hides under compute

    // S^T = K Q^T (swapped operands)
    f32x4 s[4];
#pragma unroll
    for (int ni = 0; ni < 4; ++ni) {
      s[ni] = fzero4();
      s[ni] = __builtin_amdgcn_mfma_f32_16x16x32_bf16(*(const bf16x8*)&Ks[ni * 16 + r][g * 8], qa0, s[ni], 0, 0, 0);
      s[ni] = __builtin_amdgcn_mfma_f32_16x16x32_bf16(*(const bf16x8*)&Ks[ni * 16 + r][32 + g * 8], qa1, s[ni], 0, 0, 0);
    }

    // lane (g,r) holds S[t = t0 + ni*16 + g*4 + j][q = q-row r]
    float pv[4][4];
    float pm = -1e30f;
#pragma unroll
    for (int ni = 0; ni < 4; ++ni)
#pragma unroll
      for (int j = 0; j < 4; ++j) {
        int t = t0 + ni * 16 + g * 4 + j;
        float sv = (t < NT) ? s[ni][j] : -1e30f;
        pv[ni][j] = sv;
        pm = fmaxf(pm, sv);
      }
    pm = fmaxf(pm, __shfl_xor(pm, 16));
    pm = fmaxf(pm, __shfl_xor(pm, 32));

    float mn = fmaxf(mrow, pm);
    float alpha = __expf(mrow - mn);
    mrow = mn;
    float rs = 0.f;
#pragma unroll
    for (int ni = 0; ni < 4; ++ni)
#pragma unroll
      for (int j = 0; j < 4; ++j) {
        float p = __expf(pv[ni][j] - mn);
        pv[ni][j] = p;
        rs += p;
      }
    rs += __shfl_xor(rs, 16);
    rs += __shfl_xor(rs, 32);
    lrow = lrow * alpha + rs;

    // rescale O: alpha for q = g*4+j lives at lane (g*4+j)
#pragma unroll
    for (int j = 0; j < 4; ++j) {
      float aj = __shfl(alpha, g * 4 + j);
#pragma unroll
      for (int ni = 0; ni < 4; ++ni) oacc[ni][j] *= aj;
    }

    // pack P -> bf16 pairs, one b64 write per ni (row = own q-row r)
#pragma unroll
    for (int ni = 0; ni < 4; ++ni) {
      u32x2 w;
      w[0] = (u32)f2bf(pv[ni][0]) | ((u32)f2bf(pv[ni][1]) << 16);
      w[1] = (u32)f2bf(pv[ni][2]) | ((u32)f2bf(pv[ni][3]) << 16);
      *(u32x2*)&Ps[wid][r][ni * 16 + g * 4] = w;
    }

    bf16x8 pa0 = *(const bf16x8*)&Ps[wid][r][g * 8];
    bf16x8 pa1 = *(const bf16x8*)&Ps[wid][r][32 + g * 8];
#pragma unroll
    for (int ni = 0; ni < 4; ++ni) {
      oacc[ni] = __builtin_amdgcn_mfma_f32_16x16x32_bf16(pa0, *(const bf16x8*)&Vs[ni * 16 + r][g * 8], oacc[ni], 0, 0, 0);
      oacc[ni] = __builtin_amdgcn_mfma_f32_16x16x32_bf16(pa1, *(const bf16x8*)&Vs[ni * 16 + r][32 + g * 8], oacc[ni], 0, 0, 0);
    }
  }
#undef LOADKV

  // final 1/l for q = g*4+j
  float linv[4];
#pragma unroll
  for (int j = 0; j < 4; ++j) linv[j] = 1.f / __shfl(lrow, g * 4 + j);

#pragma unroll
  for (int ni = 0; ni < 4; ++ni)
#pragma unroll
    for (int j = 0; j < 4; ++j) {
      int tq = q0 + wid * 16 + g * 4 + j;
      if (tq >= NT) continue;
      float val = oacc[ni][j] * linv[j];
      int col = h * 64 + ni * 16 + r;
      if (tq < NX)
        ox[(size_t)(b * NX + tq) * DD + col] = f2bf(val);
      else
        oc[(size_t)(b * NC + tq - NX) * DD + col] = f2bf(val);
    }
}

extern "C" void kernel_launch(void* const* d_in, const int* in_sizes, int n_in,
                              void* d_out, int out_size, void* d_ws, size_t ws_size,
                              hipStream_t stream) {
  const float* x = (const float*)d_in[0];
  const float* c = (const float*)d_in[1];
  const float* vec = (const float*)d_in[2];
  const float* w_mod = (const float*)d_in[3];
  const float* b_mod = (const float*)d_in[4];
  const float* w_qkv_x = (const float*)d_in[5];
  const float* b_qkv_x = (const float*)d_in[6];
  const float* w_qkv_c = (const float*)d_in[7];
  const float* b_qkv_c = (const float*)d_in[8];
  const float* w_proj_x = (const float*)d_in[9];
  const float* b_proj_x = (const float*)d_in[10];
  const float* w_proj_c = (const float*)d_in[11];
  const float* b_proj_c = (const float*)d_in[12];
  const float* w1_x = (const float*)d_in[13];
  const float* b1_x = (const float*)d_in[14];
  const float* w2_x = (const float*)d_in[15];
  const float* b2_x = (const float*)d_in[16];
  const float* w1_c = (const float*)d_in[17];
  const float* b1_c = (const float*)d_in[18];
  const float* w2_c = (const float*)d_in[19];
  const float* b2_c = (const float*)d_in[20];

  if (ws_size < 229195776ull) return;  // workspace layout below needs this much

  char* ws = (char*)d_ws;
  // persistent: bf16-transposed weights + mod
  u16* wt_qkv_x = (u16*)(ws + 0);
  u16* wt_qkv_c = (u16*)(ws + 14155776);
  u16* wt_proj_x = (u16*)(ws + 28311552);
  u16* wt_proj_c = (u16*)(ws + 33030144);
  u16* wt_w1_x = (u16*)(ws + 37748736);
  u16* wt_w1_c = (u16*)(ws + 56623104);
  u16* wt_w2_x = (u16*)(ws + 75497472);
  u16* wt_w2_c = (u16*)(ws + 94371840);
  float* modf = (float*)(ws + 113246208);
  char* S = ws + 113393664;
  // slot 1 (14,475,264 B): x_n/c_n -> o_x/o_c -> xln/cln -> pb0 (mlp2 partial z=0)
  u16* xn = (u16*)(S);
  u16* cn = (u16*)(S + 12582912);
  // slot 2 (43,425,792 B): qkv_x_out/qkv_c_out -> x2/c2 (f32)
  u16* qkvx = (u16*)(S + 14475264);
  u16* qkvc = (u16*)(S + 52224000);
  float* x2 = (float*)(S + 14475264);   // 25,165,824 B, ends S+39,641,088
  float* c2 = (float*)(S + 39641088);   //  3,784,704 B, ends S+43,425,792
  u16* pb0 = (u16*)(S);                 // 12,582,912 B (xn/cn dead after mlp1 reads)
  u16* pb1 = (u16*)(S + 43425792);      // 12,582,912 B (qkv outputs dead, after c2)
  // partial stride pb0 -> pb1 in u16 elements:
  const int PSTRIDE = 43425792 / 2;     // 21,712,896
  // slot 3 (57,901,056 B): q/k/vt -> h_x/h_c ; head also used as k_mod partials
  u16* qb = (u16*)(S + 57901056);
  u16* kb = (u16*)(S + 72376320);
  u16* vtb = (u16*)(S + 86851584);
  u16* hx = (u16*)(S + 57901056);
  u16* hc = (u16*)(S + 108232704);
  float* modpart = (float*)(S + 57901056);  // 884736 B, dead before q/k/vt written

  // 1) weights -> bf16 transposed
  k_transpose<<<dim3(NQKV / 32, DD / 32), 256, 0, stream>>>(w_qkv_x, wt_qkv_x, DD, NQKV);
  k_transpose<<<dim3(NQKV / 32, DD / 32), 256, 0, stream>>>(w_qkv_c, wt_qkv_c, DD, NQKV);
  k_transpose<<<dim3(DD / 32, DD / 32), 256, 0, stream>>>(w_proj_x, wt_proj_x, DD, DD);
  k_transpose<<<dim3(DD / 32, DD / 32), 256, 0, stream>>>(w_proj_c, wt_proj_c, DD, DD);
  k_transpose<<<dim3(MHD / 32, DD / 32), 256, 0, stream>>>(w1_x, wt_w1_x, DD, MHD);
  k_transpose<<<dim3(MHD / 32, DD / 32), 256, 0, stream>>>(w1_c, wt_w1_c, DD, MHD);
  k_transpose<<<dim3(DD / 32, MHD / 32), 256, 0, stream>>>(w2_x, wt_w2_x, MHD, DD);
  k_transpose<<<dim3(DD / 32, MHD / 32), 256, 0, stream>>>(w2_c, wt_w2_c, MHD, DD);

  // 2) modulation vector (split-K, deterministic two-stage)
  k_mod_part<<<dim3(NMOD / 256, KSPL), 256, 0, stream>>>(vec, w_mod, modpart);
  k_mod_red<<<dim3(NMOD / 256), 256, 0, stream>>>(modpart, b_mod, modf);

  // 3) modulated LN -> bf16
  k_ln<<<dim3(BB * NX), 256, 0, stream>>>(x, xn, modf, 0, DD, NX);
  k_ln<<<dim3(BB * NC), 256, 0, stream>>>(c, cn, modf, 3 * DD, 4 * DD, NC);

  // 4) QKV GEMMs (proven 128x128 pipelined kernel)
  k_gemm<0><<<dim3(NQKV / 128, 32), 256, 0, stream>>>(xn, wt_qkv_x, b_qkv_x, BB * NX, NQKV, DD, DD, DD, 0, qkvx, nullptr, nullptr, 0, 1);
  k_gemm<0><<<dim3(NQKV / 128, 5), 256, 0, stream>>>(cn, wt_qkv_c, b_qkv_c, BB * NC, NQKV, DD, DD, DD, 0, qkvc, nullptr, nullptr, 0, 1);

  // 5) reshape to q/k (b,h,t,d) and vt (b,h,d,t)
  k_qk<<<dim3((NT * 64 + 255) / 256, HH, BB), 256, 0, stream>>>(qkvx, qkvc, qb, kb);
  k_vt<<<dim3((NT + 63) / 64, HH, BB), 256, 0, stream>>>(qkvx, qkvc, vtb);

  // 6) flash attention (QBLK=128, 8 waves) -> o (written into slot 1)
  k_attn<<<dim3((NT + 127) / 128, HH, BB), 512, 0, stream>>>(qb, kb, vtb, xn, cn);

  // 7) output projections with gated residual -> x2/c2 f32
  k_gemm<2><<<dim3(DD / 128, 32), 256, 0, stream>>>(xn, wt_proj_x, b_proj_x, BB * NX, DD, DD, DD, DD, 0, x2, x, modf, 2 * DD, NX);
  k_gemm<2><<<dim3(DD / 128, 5), 256, 0, stream>>>(cn, wt_proj_c, b_proj_c, BB * NC, DD, DD, DD, DD, 0, c2, c, modf, 5 * DD, NC);

  // 8) plain LN -> bf16
  k_ln<<<dim3(BB * NX), 256, 0, stream>>>(x2, xn, nullptr, 0, 0, NX);
  k_ln<<<dim3(BB * NC), 256, 0, stream>>>(c2, cn, nullptr, 0, 0, NC);

  // 9) MLP (proven 128x128 pipelined kernel)
  k_gemm<1><<<dim3(MHD / 128, 32), 256, 0, stream>>>(xn, wt_w1_x, b1_x, BB * NX, MHD, DD, DD, DD, 0, hx, nullptr, nullptr, 0, 1);
  k_gemm<1><<<dim3(MHD / 128, 5), 256, 0, stream>>>(cn, wt_w1_c, b1_c, BB * NC, MHD, DD, DD, DD, 0, hc, nullptr, nullptr, 0, 1);

  float* outx = (float*)d_out;
  float* outc = outx + (size_t)BB * NX * DD;
  // mlp2_x: concurrent split-K (z=0: K[0,3072), z=1: K[3072,6144)) -> bf16
  // partials at pb0 / pb0 + PSTRIDE (== pb1, disjoint from live x2/c2) -> reduce
  k_gemm<4><<<dim3(DD / 128, 32, 2), 256, 0, stream>>>(hx, wt_w2_x, b2_x, BB * NX, DD, MHD, MHD, MHD / 2, MHD / 2, pb0, nullptr, nullptr, PSTRIDE, NX);
  k_red<<<dim3(BB * NX), 256, 0, stream>>>(pb0, pb1, x2, b2_x, outx);
  k_gemm<3><<<dim3(DD / 128, 5), 256, 0, stream>>>(hc, wt_w2_c, b2_c, BB * NC, DD, MHD, MHD, MHD, 0, outc, c2, nullptr, 0, NC);
}

// Round 10
// 759.142 us; speedup vs baseline: 3.2754x; 1.1293x over previous
//
#include <hip/hip_runtime.h>
#include <stdint.h>

typedef unsigned short u16;
typedef unsigned int u32;
typedef __attribute__((ext_vector_type(8))) short bf16x8;
typedef __attribute__((ext_vector_type(8))) unsigned short u16x8;
typedef __attribute__((ext_vector_type(2))) unsigned int u32x2;
typedef __attribute__((ext_vector_type(4))) float f32x4;

#define LB256 __launch_bounds__(256, 2)

// ---- problem dims ----
#define BB 4
#define NX 1024
#define NC 154
#define NT 1178
#define NTP 1184   // padded t stride for V^T (16B-aligned rows)
#define DD 1536
#define HH 24
#define MHD 6144
#define NQKV 4608
#define NMOD 9216
#define KSPL 6

__device__ __forceinline__ int imin(int a, int b) { return a < b ? a : b; }

__device__ __forceinline__ u16 f2bf(float f) {
  u32 u = __float_as_uint(f);
  u32 r = (u + 0x7fffu + ((u >> 16) & 1u)) >> 16;
  return (u16)r;
}

__device__ __forceinline__ float bf2f(u16 v) {
  u32 u = ((u32)v) << 16;
  return __uint_as_float(u);
}

// tanh-gelu via sigmoid identity: 0.5x(1+tanh(z)) == x * sigmoid(2z)
__device__ __forceinline__ float gelu_t(float x) {
  float u = 1.5957691216f * x * fmaf(0.044715f, x * x, 1.f);
  return x / (1.f + __expf(-u));
}

__device__ __forceinline__ f32x4 fzero4() {
  f32x4 z; z[0] = 0.f; z[1] = 0.f; z[2] = 0.f; z[3] = 0.f; return z;
}

// async global->LDS, 16B per lane; LDS dest = wave-uniform base + lane*16
__device__ __forceinline__ void glds16(const u16* g, u16* l) {
  __builtin_amdgcn_global_load_lds(
      (const __attribute__((address_space(1))) void*)g,
      (__attribute__((address_space(3))) void*)l, 16, 0, 0);
}

#define WAITV4 asm volatile("s_waitcnt vmcnt(4)" ::: "memory")
#define WAITV0 asm volatile("s_waitcnt vmcnt(0)" ::: "memory")
#define SCHEDB __builtin_amdgcn_sched_barrier(0)

// ---- weight transpose + f32->bf16: W[K][N] -> Wt[N][K] ----
__global__ void k_transpose(const float* __restrict__ W, u16* __restrict__ Wt, int K, int N) {
  __shared__ float tile[32][33];
  int n0 = blockIdx.x * 32, k0 = blockIdx.y * 32;
  int tx = threadIdx.x & 31, ty = threadIdx.x >> 5;  // 32 x 8
#pragma unroll
  for (int j = 0; j < 32; j += 8)
    tile[ty + j][tx] = W[(size_t)(k0 + ty + j) * N + n0 + tx];
  __syncthreads();
#pragma unroll
  for (int j = 0; j < 32; j += 8)
    Wt[(size_t)(n0 + ty + j) * K + k0 + tx] = f2bf(tile[tx][ty + j]);
}

// ---- mod = silu(vec) @ w_mod + b_mod : split-K partials (deterministic) ----
__global__ void k_mod_part(const float* __restrict__ vec, const float* __restrict__ w_mod,
                           float* __restrict__ part) {
  __shared__ float sv[BB][256];
  int n = blockIdx.x * 256 + threadIdx.x;
  int kb = blockIdx.y;
  int k0 = kb * 256;
  for (int i = threadIdx.x; i < BB * 256; i += 256) {
    int b = i >> 8, kk = i & 255;
    float v = vec[b * DD + k0 + kk];
    sv[b][kk] = v / (1.f + __expf(-v));
  }
  __syncthreads();
  float a0 = 0.f, a1 = 0.f, a2 = 0.f, a3 = 0.f;
  for (int k = 0; k < 256; ++k) {
    float w = w_mod[(size_t)(k0 + k) * NMOD + n];
    a0 = fmaf(sv[0][k], w, a0);
    a1 = fmaf(sv[1][k], w, a1);
    a2 = fmaf(sv[2][k], w, a2);
    a3 = fmaf(sv[3][k], w, a3);
  }
  part[((size_t)kb * BB + 0) * NMOD + n] = a0;
  part[((size_t)kb * BB + 1) * NMOD + n] = a1;
  part[((size_t)kb * BB + 2) * NMOD + n] = a2;
  part[((size_t)kb * BB + 3) * NMOD + n] = a3;
}

__global__ void k_mod_red(const float* __restrict__ part, const float* __restrict__ b_mod,
                          float* __restrict__ mod) {
  int n = blockIdx.x * 256 + threadIdx.x;
  float bb = b_mod[n];
#pragma unroll
  for (int b = 0; b < BB; ++b) {
    float s = bb;
#pragma unroll
    for (int kb = 0; kb < KSPL; ++kb) s += part[((size_t)kb * BB + b) * NMOD + n];
    mod[b * NMOD + n] = s;
  }
}

// ---- LayerNorm (optionally modulated) f32 -> bf16 ----
__global__ LB256 void k_ln(const float* __restrict__ in, u16* __restrict__ out,
                           const float* __restrict__ modp, int sh_off, int sc_off,
                           int rows_per_b) {
  int row = blockIdx.x;
  int b = row / rows_per_b;
  const float* xr = in + (size_t)row * DD;
  float v[6];
  float s = 0.f, s2 = 0.f;
#pragma unroll
  for (int i = 0; i < 6; ++i) {
    float t = xr[threadIdx.x + 256 * i];
    v[i] = t; s += t; s2 += t * t;
  }
#pragma unroll
  for (int m = 32; m >= 1; m >>= 1) {
    s += __shfl_xor(s, m);
    s2 += __shfl_xor(s2, m);
  }
  __shared__ float red[8];
  int wid = threadIdx.x >> 6;
  if ((threadIdx.x & 63) == 0) { red[wid] = s; red[4 + wid] = s2; }
  __syncthreads();
  s = red[0] + red[1] + red[2] + red[3];
  s2 = red[4] + red[5] + red[6] + red[7];
  float mean = s * (1.f / (float)DD);
  float var = s2 * (1.f / (float)DD) - mean * mean;
  float rstd = rsqrtf(var + 1e-6f);
#pragma unroll
  for (int i = 0; i < 6; ++i) {
    int d = threadIdx.x + 256 * i;
    float y = (v[i] - mean) * rstd;
    if (modp) y = y * (1.f + modp[b * NMOD + sc_off + d]) + modp[b * NMOD + sh_off + d];
    out[(size_t)row * DD + d] = f2bf(y);
  }
}

// ---- GEMM epilogue variants ----
// 0 bias->bf16 | 1 gelu->bf16 | 2 resid+g*(acc+bias)->f32 | 3 resid+acc+bias->f32
// 4 acc->bf16 partial at outp + zed*goff | 5 qkv scatter (q,k (b,h,t,d); v^T)
template <int EPI>
__device__ __forceinline__ void gemm_epi(
    const f32x4 (&acc)[4][4], int m0, int n0, int wm, int wn, int g, int r,
    int M, int N, const float* bias, void* outp, const float* resid,
    const float* modp, int goff, int rpb, int zed,
    u16* qb, u16* kb, u16* vtb) {
#pragma unroll
  for (int mi = 0; mi < 4; ++mi) {
#pragma unroll
    for (int ni = 0; ni < 4; ++ni) {
      const int col = n0 + wn + ni * 16 + r;
      float bv = 0.f;
      if constexpr (EPI != 4) bv = bias[col];
#pragma unroll
      for (int j = 0; j < 4; ++j) {
        const int row = m0 + wm + mi * 16 + g * 4 + j;
        if (row >= M) continue;
        const size_t off = (size_t)row * N + col;
        float v = acc[mi][ni][j] + bv;
        if constexpr (EPI == 0) {
          ((u16*)outp)[off] = f2bf(v);
        } else if constexpr (EPI == 1) {
          ((u16*)outp)[off] = f2bf(gelu_t(v));
        } else if constexpr (EPI == 2) {
          const int b = row / rpb;
          ((float*)outp)[off] = resid[off] + modp[b * NMOD + goff + col] * v;
        } else if constexpr (EPI == 3) {
          ((float*)outp)[off] = resid[off] + v;
        } else if constexpr (EPI == 4) {
          ((u16*)outp)[(size_t)zed * (size_t)goff + off] = f2bf(acc[mi][ni][j]);
        } else {  // 5: qkv scatter; block's 128-col span is purely q, k, or v
          const int b = row / rpb;
          const int t = goff + (row - b * rpb);
          const u16 bw = f2bf(v);
          if (col < DD) {
            const int h = col >> 6, d = col & 63;
            qb[(((size_t)b * HH + h) * NT + t) * 64 + d] = bw;
          } else if (col < 2 * DD) {
            const int cc = col - DD;
            const int h = cc >> 6, d = cc & 63;
            kb[(((size_t)b * HH + h) * NT + t) * 64 + d] = bw;
          } else {
            const int cc = col - 2 * DD;
            const int h = cc >> 6, d = cc & 63;
            vtb[((size_t)b * HH + h) * (64 * NTP) + (size_t)d * NTP + t] = bw;
          }
        }
      }
    }
  }
}

// ---- merged dual-stream pipelined bf16 MFMA GEMM, 128x128x32 tile ----
// Role 1 (m-blocks [0,yHi)) uses arg-set 1 / EPI1; role 2 uses set 2 / EPI2.
// 3-buffer LDS, counted vmcnt(4), one barrier per K-step, XOR-swizzled LDS.
template <int EPI1, int EPI2>
__global__ LB256 void k_gemm2(
    const u16* __restrict__ A1, const u16* __restrict__ Bt1, const float* __restrict__ bias1,
    int M1, int rpb1, int goff1, int kLen1,
    const u16* __restrict__ A2, const u16* __restrict__ Bt2, const float* __restrict__ bias2,
    int M2, int rpb2, int goff2, int kLen2,
    int yHi, int N, int lda, int ldb, int kzOff,
    void* __restrict__ out1, void* __restrict__ out2,
    const float* __restrict__ resid1, const float* __restrict__ resid2,
    const float* __restrict__ modp,
    u16* __restrict__ qb, u16* __restrict__ kb, u16* __restrict__ vtb) {
  __shared__ __align__(16) u16 sm[3 * 8192];  // 48 KB
  const int tid = threadIdx.x;
  const int lane = tid & 63;
  const int g = lane >> 4, r = lane & 15;
  const int wid = tid >> 6;

  // bijective XCD-aware tile remap (m204) over the full (gx x gyTotal) grid
  const int gx = gridDim.x;
  const int nwg = gx * gridDim.y;
  int wg = blockIdx.y * gx + blockIdx.x;
  {
    int q = nwg >> 3, rr = nwg & 7;
    int xcd = wg & 7, sl = wg >> 3;
    wg = (xcd < rr ? xcd * (q + 1) : rr * (q + 1) + (xcd - rr) * q) + sl;
  }
  const int mIdx = wg / gx;
  const bool role2 = mIdx >= yHi;
  if (role2 && EPI1 == 4 && blockIdx.z) return;  // split-K z only for role 1

  const u16* A = role2 ? A2 : A1;
  const u16* Bt = role2 ? Bt2 : Bt1;
  const int M = role2 ? M2 : M1;
  const int kLen = role2 ? kLen2 : kLen1;
  const int m0 = (role2 ? (mIdx - yHi) : mIdx) * 128, n0 = (wg % gx) * 128;
  const int wm = (wid >> 1) * 64, wn = (wid & 1) * 64;
  if (!role2 && kzOff) {
    A += (size_t)blockIdx.z * kzOff;
    Bt += (size_t)blockIdx.z * kzOff;
  }

  f32x4 acc[4][4];
#pragma unroll
  for (int i = 0; i < 4; ++i)
#pragma unroll
    for (int j = 0; j < 4; ++j) acc[i][j] = fzero4();

  // staging geometry (proven, 0 bank conflicts): wave wid owns chunks c0,c1;
  // lane l -> row c*16 + l/4, phys slot l&3 holds logical slot (l&3)^((l>>3)&3)
  const int rl = lane >> 2;
  const int slg = (lane & 3) ^ ((lane >> 3) & 3);
  const int c0 = wid * 2, c1 = wid * 2 + 1;
  const size_t aR0 = (size_t)imin(m0 + c0 * 16 + rl, M - 1) * lda + slg * 8;
  const size_t aR1 = (size_t)imin(m0 + c1 * 16 + rl, M - 1) * lda + slg * 8;
  const size_t bR0 = (size_t)(n0 + c0 * 16 + rl) * ldb + slg * 8;
  const size_t bR1 = (size_t)(n0 + c1 * 16 + rl) * ldb + slg * 8;

  int aOff[4], bOff[4];
#pragma unroll
  for (int mi = 0; mi < 4; ++mi) aOff[mi] = (wm + mi * 16 + r) * 32 + ((g ^ ((r >> 1) & 3)) * 8);
#pragma unroll
  for (int ni = 0; ni < 4; ++ni) bOff[ni] = 4096 + (wn + ni * 16 + r) * 32 + ((g ^ ((r >> 1) & 3)) * 8);

  const int nt = kLen >> 5;  // K-steps of 32

#define STAGE(BI, T)                                        \
  do {                                                      \
    u16* bb = &sm[(BI) * 8192];                             \
    size_t kk = (size_t)(T) * 32;                           \
    glds16(A + aR0 + kk, bb + c0 * 512);                    \
    glds16(A + aR1 + kk, bb + c1 * 512);                    \
    glds16(Bt + bR0 + kk, bb + 4096 + c0 * 512);            \
    glds16(Bt + bR1 + kk, bb + 4096 + c1 * 512);            \
  } while (0)

  STAGE(0, 0);
  STAGE(1, 1);

  for (int t = 0; t < nt - 1; ++t) {
    WAITV4;                              // my tile-t loads landed (t+1 in flight)
    __builtin_amdgcn_s_barrier();        // all waves' tile-t data published
    SCHEDB;
    if (t + 2 < nt) STAGE((t + 2) % 3, t + 2);
    const u16* bb = &sm[(t % 3) * 8192];
    bf16x8 af[4], bfr[4];
#pragma unroll
    for (int mi = 0; mi < 4; ++mi) af[mi] = *(const bf16x8*)(bb + aOff[mi]);
#pragma unroll
    for (int ni = 0; ni < 4; ++ni) bfr[ni] = *(const bf16x8*)(bb + bOff[ni]);
    __builtin_amdgcn_s_setprio(1);
#pragma unroll
    for (int mi = 0; mi < 4; ++mi)
#pragma unroll
      for (int ni = 0; ni < 4; ++ni)
        acc[mi][ni] = __builtin_amdgcn_mfma_f32_16x16x32_bf16(af[mi], bfr[ni], acc[mi][ni], 0, 0, 0);
    __builtin_amdgcn_s_setprio(0);
    SCHEDB;
  }
  {
    WAITV0;
    __builtin_amdgcn_s_barrier();
    SCHEDB;
    const u16* bb = &sm[((nt - 1) % 3) * 8192];
    bf16x8 af[4], bfr[4];
#pragma unroll
    for (int mi = 0; mi < 4; ++mi) af[mi] = *(const bf16x8*)(bb + aOff[mi]);
#pragma unroll
    for (int ni = 0; ni < 4; ++ni) bfr[ni] = *(const bf16x8*)(bb + bOff[ni]);
#pragma unroll
    for (int mi = 0; mi < 4; ++mi)
#pragma unroll
      for (int ni = 0; ni < 4; ++ni)
        acc[mi][ni] = __builtin_amdgcn_mfma_f32_16x16x32_bf16(af[mi], bfr[ni], acc[mi][ni], 0, 0, 0);
  }
#undef STAGE

  if (role2)
    gemm_epi<EPI2>(acc, m0, n0, wm, wn, g, r, M, N, bias2, out2, resid2, modp,
                   goff2, rpb2, blockIdx.z, qb, kb, vtb);
  else
    gemm_epi<EPI1>(acc, m0, n0, wm, wn, g, r, M, N, bias1, out1, resid1, modp,
                   goff1, rpb1, blockIdx.z, qb, kb, vtb);
}

// ---- split-K reduce for mlp2_x: out = resid + bias + p0 + p1 ----
__global__ void k_red(const u16* __restrict__ p0, const u16* __restrict__ p1,
                      const float* __restrict__ resid, const float* __restrict__ bias,
                      float* __restrict__ out) {
  size_t base = (size_t)blockIdx.x * DD;
#pragma unroll
  for (int i = 0; i < 6; ++i) {
    int j = threadIdx.x + 256 * i;
    out[base + j] = resid[base + j] + bias[j] + bf2f(p0[base + j]) + bf2f(p1[base + j]);
  }
}

// ---- flash attention: QBLK=128 (8 waves x 16 rows), KBLK=64, HD=64 ----
// Swapped QK^T (S^T = mfma(K,Q)): lane owns q-row (lane&15), 16 in-lane t.
// In-register softmax, packed b64 P-writes, next-tile K/V register prefetch.
__global__ __launch_bounds__(512, 2) void k_attn(
    const u16* __restrict__ q, const u16* __restrict__ kk,
    const u16* __restrict__ vt, u16* __restrict__ ox, u16* __restrict__ oc) {
  __shared__ __align__(16) u16 Ks[64][72];
  __shared__ __align__(16) u16 Vs[64][72];
  __shared__ __align__(16) u16 Ps[8][16][72];

  const int lane = threadIdx.x & 63, wid = threadIdx.x >> 6;  // wid 0..7
  const int g = lane >> 4, r = lane & 15;
  const int q0 = blockIdx.x * 128;
  const int h = blockIdx.y, b = blockIdx.z;
  const size_t bh = (size_t)b * HH + h;
  const u16* qp = q + bh * (NT * 64);
  const u16* kp = kk + bh * (NT * 64);
  const u16* vp = vt + bh * (64 * NTP);

  const int qrow = imin(q0 + wid * 16 + r, NT - 1);
  u16x8 qr0 = *(const u16x8*)(qp + (size_t)qrow * 64 + g * 8);
  u16x8 qr1 = *(const u16x8*)(qp + (size_t)qrow * 64 + 32 + g * 8);
  bf16x8 qa0, qa1;
#pragma unroll
  for (int e = 0; e < 8; ++e) {
    qa0[e] = (short)f2bf(bf2f(qr0[e]) * 0.125f);
    qa1[e] = (short)f2bf(bf2f(qr1[e]) * 0.125f);
  }

  f32x4 oacc[4];
#pragma unroll
  for (int i = 0; i < 4; ++i) oacc[i] = fzero4();
  float mrow = -1e30f, lrow = 0.f;

  const int trA = threadIdx.x >> 3;
  const int ccA = (threadIdx.x & 7) * 8;

  u16x8 kreg, vreg;
#define LOADKV(T0)                                                     \
  do {                                                                 \
    int tsrc = imin((T0) + trA, NT - 1);                               \
    kreg = *(const u16x8*)(kp + (size_t)tsrc * 64 + ccA);              \
    int tcol = (T0) + ccA;                                             \
    if (tcol + 8 <= NT) {                                              \
      vreg = *(const u16x8*)(vp + (size_t)trA * NTP + tcol);           \
    } else {                                                           \
      _Pragma("unroll")                                                \
      for (int e = 0; e < 8; ++e)                                      \
        vreg[e] = vp[(size_t)trA * NTP + imin(tcol + e, NT - 1)];      \
    }                                                                  \
  } while (0)

  LOADKV(0);

  for (int t0 = 0; t0 < NT; t0 += 64) {
    if (t0) __syncthreads();
    *(u16x8*)&Ks[trA][ccA] = kreg;
    *(u16x8*)&Vs[trA][ccA] = vreg;
    __syncthreads();
    if (t0 + 64 < NT) LOADKV(t0 + 64);

    f32x4 s[4];
#pragma unroll
    for (int ni = 0; ni < 4; ++ni) {
      s[ni] = fzero4();
      s[ni] = __builtin_amdgcn_mfma_f32_16x16x32_bf16(*(const bf16x8*)&Ks[ni * 16 + r][g * 8], qa0, s[ni], 0, 0, 0);
      s[ni] = __builtin_amdgcn_mfma_f32_16x16x32_bf16(*(const bf16x8*)&Ks[ni * 16 + r][32 + g * 8], qa1, s[ni], 0, 0, 0);
    }

    float pv[4][4];
    float pm = -1e30f;
#pragma unroll
    for (int ni = 0; ni < 4; ++ni)
#pragma unroll
      for (int j = 0; j < 4; ++j) {
        int t = t0 + ni * 16 + g * 4 + j;
        float sv = (t < NT) ? s[ni][j] : -1e30f;
        pv[ni][j] = sv;
        pm = fmaxf(pm, sv);
      }
    pm = fmaxf(pm, __shfl_xor(pm, 16));
    pm = fmaxf(pm, __shfl_xor(pm, 32));

    float mn = fmaxf(mrow, pm);
    float alpha = __expf(mrow - mn);
    mrow = mn;
    float rs = 0.f;
#pragma unroll
    for (int ni = 0; ni < 4; ++ni)
#pragma unroll
      for (int j = 0; j < 4; ++j) {
        float p = __expf(pv[ni][j] - mn);
        pv[ni][j] = p;
        rs += p;
      }
    rs += __shfl_xor(rs, 16);
    rs += __shfl_xor(rs, 32);
    lrow = lrow * alpha + rs;

#pragma unroll
    for (int j = 0; j < 4; ++j) {
      float aj = __shfl(alpha, g * 4 + j);
#pragma unroll
      for (int ni = 0; ni < 4; ++ni) oacc[ni][j] *= aj;
    }

#pragma unroll
    for (int ni = 0; ni < 4; ++ni) {
      u32x2 w;
      w[0] = (u32)f2bf(pv[ni][0]) | ((u32)f2bf(pv[ni][1]) << 16);
      w[1] = (u32)f2bf(pv[ni][2]) | ((u32)f2bf(pv[ni][3]) << 16);
      *(u32x2*)&Ps[wid][r][ni * 16 + g * 4] = w;
    }

    bf16x8 pa0 = *(const bf16x8*)&Ps[wid][r][g * 8];
    bf16x8 pa1 = *(const bf16x8*)&Ps[wid][r][32 + g * 8];
#pragma unroll
    for (int ni = 0; ni < 4; ++ni) {
      oacc[ni] = __builtin_amdgcn_mfma_f32_16x16x32_bf16(pa0, *(const bf16x8*)&Vs[ni * 16 + r][g * 8], oacc[ni], 0, 0, 0);
      oacc[ni] = __builtin_amdgcn_mfma_f32_16x16x32_bf16(pa1, *(const bf16x8*)&Vs[ni * 16 + r][32 + g * 8], oacc[ni], 0, 0, 0);
    }
  }
#undef LOADKV

  float linv[4];
#pragma unroll
  for (int j = 0; j < 4; ++j) linv[j] = 1.f / __shfl(lrow, g * 4 + j);

#pragma unroll
  for (int ni = 0; ni < 4; ++ni)
#pragma unroll
    for (int j = 0; j < 4; ++j) {
      int tq = q0 + wid * 16 + g * 4 + j;
      if (tq >= NT) continue;
      float val = oacc[ni][j] * linv[j];
      int col = h * 64 + ni * 16 + r;
      if (tq < NX)
        ox[(size_t)(b * NX + tq) * DD + col] = f2bf(val);
      else
        oc[(size_t)(b * NC + tq - NX) * DD + col] = f2bf(val);
    }
}

extern "C" void kernel_launch(void* const* d_in, const int* in_sizes, int n_in,
                              void* d_out, int out_size, void* d_ws, size_t ws_size,
                              hipStream_t stream) {
  const float* x = (const float*)d_in[0];
  const float* c = (const float*)d_in[1];
  const float* vec = (const float*)d_in[2];
  const float* w_mod = (const float*)d_in[3];
  const float* b_mod = (const float*)d_in[4];
  const float* w_qkv_x = (const float*)d_in[5];
  const float* b_qkv_x = (const float*)d_in[6];
  const float* w_qkv_c = (const float*)d_in[7];
  const float* b_qkv_c = (const float*)d_in[8];
  const float* w_proj_x = (const float*)d_in[9];
  const float* b_proj_x = (const float*)d_in[10];
  const float* w_proj_c = (const float*)d_in[11];
  const float* b_proj_c = (const float*)d_in[12];
  const float* w1_x = (const float*)d_in[13];
  const float* b1_x = (const float*)d_in[14];
  const float* w2_x = (const float*)d_in[15];
  const float* b2_x = (const float*)d_in[16];
  const float* w1_c = (const float*)d_in[17];
  const float* b1_c = (const float*)d_in[18];
  const float* w2_c = (const float*)d_in[19];
  const float* b2_c = (const float*)d_in[20];

  if (ws_size < 229195776ull) return;  // workspace layout below needs this much

  char* ws = (char*)d_ws;
  // persistent: bf16-transposed weights + mod
  u16* wt_qkv_x = (u16*)(ws + 0);
  u16* wt_qkv_c = (u16*)(ws + 14155776);
  u16* wt_proj_x = (u16*)(ws + 28311552);
  u16* wt_proj_c = (u16*)(ws + 33030144);
  u16* wt_w1_x = (u16*)(ws + 37748736);
  u16* wt_w1_c = (u16*)(ws + 56623104);
  u16* wt_w2_x = (u16*)(ws + 75497472);
  u16* wt_w2_c = (u16*)(ws + 94371840);
  float* modf = (float*)(ws + 113246208);
  char* S = ws + 113393664;
  // slot 1 (14,475,264 B): x_n/c_n -> o_x/o_c -> xln/cln -> pb0 (mlp2 partial z=0)
  u16* xn = (u16*)(S);
  u16* cn = (u16*)(S + 12582912);
  // slot 2 (43,425,792 B): x2/c2 (f32) + pb1
  float* x2 = (float*)(S + 14475264);   // 25,165,824 B, ends S+39,641,088
  float* c2 = (float*)(S + 39641088);   //  3,784,704 B, ends S+43,425,792
  u16* pb0 = (u16*)(S);                 // 12,582,912 B (xn/cn dead after mlp1 reads)
  u16* pb1 = (u16*)(S + 43425792);      // 12,582,912 B (dead region, after c2)
  const int PSTRIDE = 43425792 / 2;     // u16 stride pb0 -> pb1
  // slot 3 (57,901,056 B): q/k/vt -> h_x/h_c ; head also used as k_mod partials
  u16* qb = (u16*)(S + 57901056);
  u16* kb = (u16*)(S + 72376320);
  u16* vtb = (u16*)(S + 86851584);
  u16* hx = (u16*)(S + 57901056);
  u16* hc = (u16*)(S + 108232704);
  float* modpart = (float*)(S + 57901056);  // dead before q/k/vt written

  // 1) weights -> bf16 transposed
  k_transpose<<<dim3(NQKV / 32, DD / 32), 256, 0, stream>>>(w_qkv_x, wt_qkv_x, DD, NQKV);
  k_transpose<<<dim3(NQKV / 32, DD / 32), 256, 0, stream>>>(w_qkv_c, wt_qkv_c, DD, NQKV);
  k_transpose<<<dim3(DD / 32, DD / 32), 256, 0, stream>>>(w_proj_x, wt_proj_x, DD, DD);
  k_transpose<<<dim3(DD / 32, DD / 32), 256, 0, stream>>>(w_proj_c, wt_proj_c, DD, DD);
  k_transpose<<<dim3(MHD / 32, DD / 32), 256, 0, stream>>>(w1_x, wt_w1_x, DD, MHD);
  k_transpose<<<dim3(MHD / 32, DD / 32), 256, 0, stream>>>(w1_c, wt_w1_c, DD, MHD);
  k_transpose<<<dim3(DD / 32, MHD / 32), 256, 0, stream>>>(w2_x, wt_w2_x, MHD, DD);
  k_transpose<<<dim3(DD / 32, MHD / 32), 256, 0, stream>>>(w2_c, wt_w2_c, MHD, DD);

  // 2) modulation vector (split-K, deterministic two-stage)
  k_mod_part<<<dim3(NMOD / 256, KSPL), 256, 0, stream>>>(vec, w_mod, modpart);
  k_mod_red<<<dim3(NMOD / 256), 256, 0, stream>>>(modpart, b_mod, modf);

  // 3) modulated LN -> bf16
  k_ln<<<dim3(BB * NX), 256, 0, stream>>>(x, xn, modf, 0, DD, NX);
  k_ln<<<dim3(BB * NC), 256, 0, stream>>>(c, cn, modf, 3 * DD, 4 * DD, NC);

  // 4) merged QKV GEMM (x+c) with scatter epilogue -> qb,kb,vtb directly
  k_gemm2<5, 5><<<dim3(NQKV / 128, 37), 256, 0, stream>>>(
      xn, wt_qkv_x, b_qkv_x, BB * NX, NX, 0, DD,
      cn, wt_qkv_c, b_qkv_c, BB * NC, NC, NX, DD,
      32, NQKV, DD, DD, 0, nullptr, nullptr, nullptr, nullptr, nullptr,
      qb, kb, vtb);

  // 5) flash attention (QBLK=128, 8 waves) -> o (written into slot 1)
  k_attn<<<dim3((NT + 127) / 128, HH, BB), 512, 0, stream>>>(qb, kb, vtb, xn, cn);

  // 6) merged output projections with gated residual -> x2/c2 f32
  k_gemm2<2, 2><<<dim3(DD / 128, 37), 256, 0, stream>>>(
      xn, wt_proj_x, b_proj_x, BB * NX, NX, 2 * DD, DD,
      cn, wt_proj_c, b_proj_c, BB * NC, NC, 5 * DD, DD,
      32, DD, DD, DD, 0, x2, c2, x, c, modf, nullptr, nullptr, nullptr);

  // 7) plain LN -> bf16
  k_ln<<<dim3(BB * NX), 256, 0, stream>>>(x2, xn, nullptr, 0, 0, NX);
  k_ln<<<dim3(BB * NC), 256, 0, stream>>>(c2, cn, nullptr, 0, 0, NC);

  // 8) merged MLP-1 (gelu) -> hx/hc
  k_gemm2<1, 1><<<dim3(MHD / 128, 37), 256, 0, stream>>>(
      xn, wt_w1_x, b1_x, BB * NX, NX, 0, DD,
      cn, wt_w1_c, b1_c, BB * NC, NC, 0, DD,
      32, MHD, DD, DD, 0, hx, hc, nullptr, nullptr, nullptr, nullptr, nullptr, nullptr);

  float* outx = (float*)d_out;
  float* outc = outx + (size_t)BB * NX * DD;
  // 9) merged MLP-2: x = concurrent split-K partials (z=0/1), c = full-K f32 out
  k_gemm2<4, 3><<<dim3(DD / 128, 37, 2), 256, 0, stream>>>(
      hx, wt_w2_x, b2_x, BB * NX, NX, PSTRIDE, MHD / 2,
      hc, wt_w2_c, b2_c, BB * NC, NC, 0, MHD,
      32, DD, MHD, MHD, MHD / 2, pb0, outc, nullptr, c2, nullptr,
      nullptr, nullptr, nullptr);
  k_red<<<dim3(BB * NX), 256, 0, stream>>>(pb0, pb1, x2, b2_x, outx);
}

// Round 11
// 688.966 us; speedup vs baseline: 3.6091x; 1.1019x over previous
//
#include <hip/hip_runtime.h>
#include <stdint.h>

typedef unsigned short u16;
typedef unsigned int u32;
typedef __attribute__((ext_vector_type(8))) short bf16x8;
typedef __attribute__((ext_vector_type(8))) unsigned short u16x8;
typedef __attribute__((ext_vector_type(2))) unsigned int u32x2;
typedef __attribute__((ext_vector_type(4))) float f32x4;

#define LB256 __launch_bounds__(256, 2)

// ---- problem dims ----
#define BB 4
#define NX 1024
#define NC 154
#define NT 1178
#define NTP 1184   // padded t stride for V^T (16B-aligned rows)
#define DD 1536
#define HH 24
#define MHD 6144
#define NQKV 4608
#define NMOD 9216
#define KSPL 6

__device__ __forceinline__ int imin(int a, int b) { return a < b ? a : b; }

__device__ __forceinline__ u16 f2bf(float f) {
  u32 u = __float_as_uint(f);
  u32 r = (u + 0x7fffu + ((u >> 16) & 1u)) >> 16;
  return (u16)r;
}

__device__ __forceinline__ float bf2f(u16 v) {
  u32 u = ((u32)v) << 16;
  return __uint_as_float(u);
}

// tanh-gelu via sigmoid identity: 0.5x(1+tanh(z)) == x * sigmoid(2z)
__device__ __forceinline__ float gelu_t(float x) {
  float u = 1.5957691216f * x * fmaf(0.044715f, x * x, 1.f);
  return x / (1.f + __expf(-u));
}

__device__ __forceinline__ f32x4 fzero4() {
  f32x4 z; z[0] = 0.f; z[1] = 0.f; z[2] = 0.f; z[3] = 0.f; return z;
}

// async global->LDS, 16B per lane; LDS dest = wave-uniform base + lane*16
__device__ __forceinline__ void glds16(const u16* g, u16* l) {
  __builtin_amdgcn_global_load_lds(
      (const __attribute__((address_space(1))) void*)g,
      (__attribute__((address_space(3))) void*)l, 16, 0, 0);
}

#define WAITV4 asm volatile("s_waitcnt vmcnt(4)" ::: "memory")
#define WAITV0 asm volatile("s_waitcnt vmcnt(0)" ::: "memory")
#define SCHEDB __builtin_amdgcn_sched_barrier(0)

// ---- batched weight transpose + f32->bf16: 8 matrices, one dispatch ----
struct TDesc {
  const float* W[8];
  u16* Wt[8];
  int K[8];
  int N[8];
  int off[9];  // prefix block offsets
};

__global__ void k_transpose8(TDesc d) {
  __shared__ float tile[32][33];
  int bid = blockIdx.x;
  int i = 0;
#pragma unroll
  for (int t = 1; t < 8; ++t)
    if (bid >= d.off[t]) i = t;
  const float* W = d.W[i];
  u16* Wt = d.Wt[i];
  const int K = d.K[i], N = d.N[i];
  const int local = bid - d.off[i];
  const int nbx = N >> 5;
  const int n0 = (local % nbx) * 32, k0 = (local / nbx) * 32;
  int tx = threadIdx.x & 31, ty = threadIdx.x >> 5;  // 32 x 8
#pragma unroll
  for (int j = 0; j < 32; j += 8)
    tile[ty + j][tx] = W[(size_t)(k0 + ty + j) * N + n0 + tx];
  __syncthreads();
#pragma unroll
  for (int j = 0; j < 32; j += 8)
    Wt[(size_t)(n0 + ty + j) * K + k0 + tx] = f2bf(tile[tx][ty + j]);
}

// ---- mod = silu(vec) @ w_mod + b_mod : split-K partials (deterministic) ----
__global__ void k_mod_part(const float* __restrict__ vec, const float* __restrict__ w_mod,
                           float* __restrict__ part) {
  __shared__ float sv[BB][256];
  int n = blockIdx.x * 256 + threadIdx.x;
  int kb = blockIdx.y;
  int k0 = kb * 256;
  for (int i = threadIdx.x; i < BB * 256; i += 256) {
    int b = i >> 8, kk = i & 255;
    float v = vec[b * DD + k0 + kk];
    sv[b][kk] = v / (1.f + __expf(-v));
  }
  __syncthreads();
  float a0 = 0.f, a1 = 0.f, a2 = 0.f, a3 = 0.f;
  for (int k = 0; k < 256; ++k) {
    float w = w_mod[(size_t)(k0 + k) * NMOD + n];
    a0 = fmaf(sv[0][k], w, a0);
    a1 = fmaf(sv[1][k], w, a1);
    a2 = fmaf(sv[2][k], w, a2);
    a3 = fmaf(sv[3][k], w, a3);
  }
  part[((size_t)kb * BB + 0) * NMOD + n] = a0;
  part[((size_t)kb * BB + 1) * NMOD + n] = a1;
  part[((size_t)kb * BB + 2) * NMOD + n] = a2;
  part[((size_t)kb * BB + 3) * NMOD + n] = a3;
}

__global__ void k_mod_red(const float* __restrict__ part, const float* __restrict__ b_mod,
                          float* __restrict__ mod) {
  int n = blockIdx.x * 256 + threadIdx.x;
  float bb = b_mod[n];
#pragma unroll
  for (int b = 0; b < BB; ++b) {
    float s = bb;
#pragma unroll
    for (int kb = 0; kb < KSPL; ++kb) s += part[((size_t)kb * BB + b) * NMOD + n];
    mod[b * NMOD + n] = s;
  }
}

// ---- LayerNorm (optionally modulated) f32 -> bf16 ----
__global__ LB256 void k_ln(const float* __restrict__ in, u16* __restrict__ out,
                           const float* __restrict__ modp, int sh_off, int sc_off,
                           int rows_per_b) {
  int row = blockIdx.x;
  int b = row / rows_per_b;
  const float* xr = in + (size_t)row * DD;
  float v[6];
  float s = 0.f, s2 = 0.f;
#pragma unroll
  for (int i = 0; i < 6; ++i) {
    float t = xr[threadIdx.x + 256 * i];
    v[i] = t; s += t; s2 += t * t;
  }
#pragma unroll
  for (int m = 32; m >= 1; m >>= 1) {
    s += __shfl_xor(s, m);
    s2 += __shfl_xor(s2, m);
  }
  __shared__ float red[8];
  int wid = threadIdx.x >> 6;
  if ((threadIdx.x & 63) == 0) { red[wid] = s; red[4 + wid] = s2; }
  __syncthreads();
  s = red[0] + red[1] + red[2] + red[3];
  s2 = red[4] + red[5] + red[6] + red[7];
  float mean = s * (1.f / (float)DD);
  float var = s2 * (1.f / (float)DD) - mean * mean;
  float rstd = rsqrtf(var + 1e-6f);
#pragma unroll
  for (int i = 0; i < 6; ++i) {
    int d = threadIdx.x + 256 * i;
    float y = (v[i] - mean) * rstd;
    if (modp) y = y * (1.f + modp[b * NMOD + sc_off + d]) + modp[b * NMOD + sh_off + d];
    out[(size_t)row * DD + d] = f2bf(y);
  }
}

// ---- GEMM epilogue variants ----
// 0 bias->bf16 | 1 gelu->bf16 | 2 resid+g*(acc+bias)->f32 | 3 resid+acc+bias->f32
// 4 acc->bf16 partial at outp + zed*goff | 5 qkv scatter (q,k (b,h,t,d); v^T)
template <int EPI>
__device__ __forceinline__ void gemm_epi(
    const f32x4 (&acc)[4][4], int m0, int n0, int wm, int wn, int g, int r,
    int M, int N, const float* bias, void* outp, const float* resid,
    const float* modp, int goff, int rpb, int zed,
    u16* qb, u16* kb, u16* vtb) {
#pragma unroll
  for (int mi = 0; mi < 4; ++mi) {
#pragma unroll
    for (int ni = 0; ni < 4; ++ni) {
      const int col = n0 + wn + ni * 16 + r;
      float bv = 0.f;
      if constexpr (EPI != 4) bv = bias[col];
#pragma unroll
      for (int j = 0; j < 4; ++j) {
        const int row = m0 + wm + mi * 16 + g * 4 + j;
        if (row >= M) continue;
        const size_t off = (size_t)row * N + col;
        float v = acc[mi][ni][j] + bv;
        if constexpr (EPI == 0) {
          ((u16*)outp)[off] = f2bf(v);
        } else if constexpr (EPI == 1) {
          ((u16*)outp)[off] = f2bf(gelu_t(v));
        } else if constexpr (EPI == 2) {
          const int b = row / rpb;
          ((float*)outp)[off] = resid[off] + modp[b * NMOD + goff + col] * v;
        } else if constexpr (EPI == 3) {
          ((float*)outp)[off] = resid[off] + v;
        } else if constexpr (EPI == 4) {
          ((u16*)outp)[(size_t)zed * (size_t)goff + off] = f2bf(acc[mi][ni][j]);
        } else {  // 5: qkv scatter; block's 128-col span is purely q, k, or v
          const int b = row / rpb;
          const int t = goff + (row - b * rpb);
          const u16 bw = f2bf(v);
          if (col < DD) {
            const int h = col >> 6, d = col & 63;
            qb[(((size_t)b * HH + h) * NT + t) * 64 + d] = bw;
          } else if (col < 2 * DD) {
            const int cc = col - DD;
            const int h = cc >> 6, d = cc & 63;
            kb[(((size_t)b * HH + h) * NT + t) * 64 + d] = bw;
          } else {
            const int cc = col - 2 * DD;
            const int h = cc >> 6, d = cc & 63;
            vtb[((size_t)b * HH + h) * (64 * NTP) + (size_t)d * NTP + t] = bw;
          }
        }
      }
    }
  }
}

// ---- merged dual-stream pipelined bf16 MFMA GEMM, 128x128x32 tile ----
// Role 1 (m-blocks [0,yHi)) uses arg-set 1 / EPI1; role 2 uses set 2 / EPI2.
// blockIdx.z split-K (kzOff element offset) applies to BOTH roles.
// 3-buffer LDS, counted vmcnt(4), one barrier per K-step, XOR-swizzled LDS.
template <int EPI1, int EPI2>
__global__ LB256 void k_gemm2(
    const u16* __restrict__ A1, const u16* __restrict__ Bt1, const float* __restrict__ bias1,
    int M1, int rpb1, int goff1, int kLen1,
    const u16* __restrict__ A2, const u16* __restrict__ Bt2, const float* __restrict__ bias2,
    int M2, int rpb2, int goff2, int kLen2,
    int yHi, int N, int lda, int ldb, int kzOff,
    void* __restrict__ out1, void* __restrict__ out2,
    const float* __restrict__ resid1, const float* __restrict__ resid2,
    const float* __restrict__ modp,
    u16* __restrict__ qb, u16* __restrict__ kb, u16* __restrict__ vtb) {
  __shared__ __align__(16) u16 sm[3 * 8192];  // 48 KB
  const int tid = threadIdx.x;
  const int lane = tid & 63;
  const int g = lane >> 4, r = lane & 15;
  const int wid = tid >> 6;

  // bijective XCD-aware tile remap (m204) over the full (gx x gyTotal) grid
  const int gx = gridDim.x;
  const int nwg = gx * gridDim.y;
  int wg = blockIdx.y * gx + blockIdx.x;
  {
    int q = nwg >> 3, rr = nwg & 7;
    int xcd = wg & 7, sl = wg >> 3;
    wg = (xcd < rr ? xcd * (q + 1) : rr * (q + 1) + (xcd - rr) * q) + sl;
  }
  const int mIdx = wg / gx;
  const bool role2 = mIdx >= yHi;

  const u16* A = role2 ? A2 : A1;
  const u16* Bt = role2 ? Bt2 : Bt1;
  const int M = role2 ? M2 : M1;
  const int kLen = role2 ? kLen2 : kLen1;
  const int m0 = (role2 ? (mIdx - yHi) : mIdx) * 128, n0 = (wg % gx) * 128;
  const int wm = (wid >> 1) * 64, wn = (wid & 1) * 64;
  A += (size_t)blockIdx.z * kzOff;
  Bt += (size_t)blockIdx.z * kzOff;

  f32x4 acc[4][4];
#pragma unroll
  for (int i = 0; i < 4; ++i)
#pragma unroll
    for (int j = 0; j < 4; ++j) acc[i][j] = fzero4();

  // staging geometry (proven, 0 bank conflicts): wave wid owns chunks c0,c1;
  // lane l -> row c*16 + l/4, phys slot l&3 holds logical slot (l&3)^((l>>3)&3)
  const int rl = lane >> 2;
  const int slg = (lane & 3) ^ ((lane >> 3) & 3);
  const int c0 = wid * 2, c1 = wid * 2 + 1;
  const size_t aR0 = (size_t)imin(m0 + c0 * 16 + rl, M - 1) * lda + slg * 8;
  const size_t aR1 = (size_t)imin(m0 + c1 * 16 + rl, M - 1) * lda + slg * 8;
  const size_t bR0 = (size_t)(n0 + c0 * 16 + rl) * ldb + slg * 8;
  const size_t bR1 = (size_t)(n0 + c1 * 16 + rl) * ldb + slg * 8;

  int aOff[4], bOff[4];
#pragma unroll
  for (int mi = 0; mi < 4; ++mi) aOff[mi] = (wm + mi * 16 + r) * 32 + ((g ^ ((r >> 1) & 3)) * 8);
#pragma unroll
  for (int ni = 0; ni < 4; ++ni) bOff[ni] = 4096 + (wn + ni * 16 + r) * 32 + ((g ^ ((r >> 1) & 3)) * 8);

  const int nt = kLen >> 5;  // K-steps of 32

#define STAGE(BI, T)                                        \
  do {                                                      \
    u16* bb = &sm[(BI) * 8192];                             \
    size_t kk = (size_t)(T) * 32;                           \
    glds16(A + aR0 + kk, bb + c0 * 512);                    \
    glds16(A + aR1 + kk, bb + c1 * 512);                    \
    glds16(Bt + bR0 + kk, bb + 4096 + c0 * 512);            \
    glds16(Bt + bR1 + kk, bb + 4096 + c1 * 512);            \
  } while (0)

  STAGE(0, 0);
  STAGE(1, 1);

  for (int t = 0; t < nt - 1; ++t) {
    WAITV4;                              // my tile-t loads landed (t+1 in flight)
    __builtin_amdgcn_s_barrier();        // all waves' tile-t data published
    SCHEDB;
    if (t + 2 < nt) STAGE((t + 2) % 3, t + 2);
    const u16* bb = &sm[(t % 3) * 8192];
    bf16x8 af[4], bfr[4];
#pragma unroll
    for (int mi = 0; mi < 4; ++mi) af[mi] = *(const bf16x8*)(bb + aOff[mi]);
#pragma unroll
    for (int ni = 0; ni < 4; ++ni) bfr[ni] = *(const bf16x8*)(bb + bOff[ni]);
    __builtin_amdgcn_s_setprio(1);
#pragma unroll
    for (int mi = 0; mi < 4; ++mi)
#pragma unroll
      for (int ni = 0; ni < 4; ++ni)
        acc[mi][ni] = __builtin_amdgcn_mfma_f32_16x16x32_bf16(af[mi], bfr[ni], acc[mi][ni], 0, 0, 0);
    __builtin_amdgcn_s_setprio(0);
    SCHEDB;
  }
  {
    WAITV0;
    __builtin_amdgcn_s_barrier();
    SCHEDB;
    const u16* bb = &sm[((nt - 1) % 3) * 8192];
    bf16x8 af[4], bfr[4];
#pragma unroll
    for (int mi = 0; mi < 4; ++mi) af[mi] = *(const bf16x8*)(bb + aOff[mi]);
#pragma unroll
    for (int ni = 0; ni < 4; ++ni) bfr[ni] = *(const bf16x8*)(bb + bOff[ni]);
#pragma unroll
    for (int mi = 0; mi < 4; ++mi)
#pragma unroll
      for (int ni = 0; ni < 4; ++ni)
        acc[mi][ni] = __builtin_amdgcn_mfma_f32_16x16x32_bf16(af[mi], bfr[ni], acc[mi][ni], 0, 0, 0);
  }
#undef STAGE

  if (role2)
    gemm_epi<EPI2>(acc, m0, n0, wm, wn, g, r, M, N, bias2, out2, resid2, modp,
                   goff2, rpb2, blockIdx.z, qb, kb, vtb);
  else
    gemm_epi<EPI1>(acc, m0, n0, wm, wn, g, r, M, N, bias1, out1, resid1, modp,
                   goff1, rpb1, blockIdx.z, qb, kb, vtb);
}

// ---- split-K reduce for mlp2 (x rows then c rows) ----
__global__ void k_red2(const u16* __restrict__ p0x, const u16* __restrict__ p1x,
                       const float* __restrict__ residx, const float* __restrict__ bx,
                       const u16* __restrict__ p0c, const u16* __restrict__ p1c,
                       const float* __restrict__ residc, const float* __restrict__ bc,
                       float* __restrict__ outx, float* __restrict__ outc) {
  int row = blockIdx.x;
  if (row < BB * NX) {
    size_t base = (size_t)row * DD;
#pragma unroll
    for (int i = 0; i < 6; ++i) {
      int j = threadIdx.x + 256 * i;
      outx[base + j] = residx[base + j] + bx[j] + bf2f(p0x[base + j]) + bf2f(p1x[base + j]);
    }
  } else {
    size_t base = (size_t)(row - BB * NX) * DD;
#pragma unroll
    for (int i = 0; i < 6; ++i) {
      int j = threadIdx.x + 256 * i;
      outc[base + j] = residc[base + j] + bc[j] + bf2f(p0c[base + j]) + bf2f(p1c[base + j]);
    }
  }
}

// ---- flash attention: QBLK=128 (8 waves x 16 rows), KBLK=64, HD=64 ----
// Swapped QK^T (S^T = mfma(K,Q)): lane owns q-row (lane&15), 16 in-lane t.
// In-register softmax, packed b64 P-writes, next-tile K/V register prefetch.
__global__ __launch_bounds__(512, 2) void k_attn(
    const u16* __restrict__ q, const u16* __restrict__ kk,
    const u16* __restrict__ vt, u16* __restrict__ ox, u16* __restrict__ oc) {
  __shared__ __align__(16) u16 Ks[64][72];
  __shared__ __align__(16) u16 Vs[64][72];
  __shared__ __align__(16) u16 Ps[8][16][72];

  const int lane = threadIdx.x & 63, wid = threadIdx.x >> 6;  // wid 0..7
  const int g = lane >> 4, r = lane & 15;
  const int q0 = blockIdx.x * 128;
  const int h = blockIdx.y, b = blockIdx.z;
  const size_t bh = (size_t)b * HH + h;
  const u16* qp = q + bh * (NT * 64);
  const u16* kp = kk + bh * (NT * 64);
  const u16* vp = vt + bh * (64 * NTP);

  const int qrow = imin(q0 + wid * 16 + r, NT - 1);
  u16x8 qr0 = *(const u16x8*)(qp + (size_t)qrow * 64 + g * 8);
  u16x8 qr1 = *(const u16x8*)(qp + (size_t)qrow * 64 + 32 + g * 8);
  bf16x8 qa0, qa1;
#pragma unroll
  for (int e = 0; e < 8; ++e) {
    qa0[e] = (short)f2bf(bf2f(qr0[e]) * 0.125f);
    qa1[e] = (short)f2bf(bf2f(qr1[e]) * 0.125f);
  }

  f32x4 oacc[4];
#pragma unroll
  for (int i = 0; i < 4; ++i) oacc[i] = fzero4();
  float mrow = -1e30f, lrow = 0.f;

  const int trA = threadIdx.x >> 3;
  const int ccA = (threadIdx.x & 7) * 8;

  u16x8 kreg, vreg;
#define LOADKV(T0)                                                     \
  do {                                                                 \
    int tsrc = imin((T0) + trA, NT - 1);                               \
    kreg = *(const u16x8*)(kp + (size_t)tsrc * 64 + ccA);              \
    int tcol = (T0) + ccA;                                             \
    if (tcol + 8 <= NT) {                                              \
      vreg = *(const u16x8*)(vp + (size_t)trA * NTP + tcol);           \
    } else {                                                           \
      _Pragma("unroll")                                                \
      for (int e = 0; e < 8; ++e)                                      \
        vreg[e] = vp[(size_t)trA * NTP + imin(tcol + e, NT - 1)];      \
    }                                                                  \
  } while (0)

  LOADKV(0);

  for (int t0 = 0; t0 < NT; t0 += 64) {
    if (t0) __syncthreads();
    *(u16x8*)&Ks[trA][ccA] = kreg;
    *(u16x8*)&Vs[trA][ccA] = vreg;
    __syncthreads();
    if (t0 + 64 < NT) LOADKV(t0 + 64);

    f32x4 s[4];
#pragma unroll
    for (int ni = 0; ni < 4; ++ni) {
      s[ni] = fzero4();
      s[ni] = __builtin_amdgcn_mfma_f32_16x16x32_bf16(*(const bf16x8*)&Ks[ni * 16 + r][g * 8], qa0, s[ni], 0, 0, 0);
      s[ni] = __builtin_amdgcn_mfma_f32_16x16x32_bf16(*(const bf16x8*)&Ks[ni * 16 + r][32 + g * 8], qa1, s[ni], 0, 0, 0);
    }

    float pv[4][4];
    float pm = -1e30f;
#pragma unroll
    for (int ni = 0; ni < 4; ++ni)
#pragma unroll
      for (int j = 0; j < 4; ++j) {
        int t = t0 + ni * 16 + g * 4 + j;
        float sv = (t < NT) ? s[ni][j] : -1e30f;
        pv[ni][j] = sv;
        pm = fmaxf(pm, sv);
      }
    pm = fmaxf(pm, __shfl_xor(pm, 16));
    pm = fmaxf(pm, __shfl_xor(pm, 32));

    float mn = fmaxf(mrow, pm);
    float alpha = __expf(mrow - mn);
    mrow = mn;
    float rs = 0.f;
#pragma unroll
    for (int ni = 0; ni < 4; ++ni)
#pragma unroll
      for (int j = 0; j < 4; ++j) {
        float p = __expf(pv[ni][j] - mn);
        pv[ni][j] = p;
        rs += p;
      }
    rs += __shfl_xor(rs, 16);
    rs += __shfl_xor(rs, 32);
    lrow = lrow * alpha + rs;

#pragma unroll
    for (int j = 0; j < 4; ++j) {
      float aj = __shfl(alpha, g * 4 + j);
#pragma unroll
      for (int ni = 0; ni < 4; ++ni) oacc[ni][j] *= aj;
    }

#pragma unroll
    for (int ni = 0; ni < 4; ++ni) {
      u32x2 w;
      w[0] = (u32)f2bf(pv[ni][0]) | ((u32)f2bf(pv[ni][1]) << 16);
      w[1] = (u32)f2bf(pv[ni][2]) | ((u32)f2bf(pv[ni][3]) << 16);
      *(u32x2*)&Ps[wid][r][ni * 16 + g * 4] = w;
    }

    bf16x8 pa0 = *(const bf16x8*)&Ps[wid][r][g * 8];
    bf16x8 pa1 = *(const bf16x8*)&Ps[wid][r][32 + g * 8];
#pragma unroll
    for (int ni = 0; ni < 4; ++ni) {
      oacc[ni] = __builtin_amdgcn_mfma_f32_16x16x32_bf16(pa0, *(const bf16x8*)&Vs[ni * 16 + r][g * 8], oacc[ni], 0, 0, 0);
      oacc[ni] = __builtin_amdgcn_mfma_f32_16x16x32_bf16(pa1, *(const bf16x8*)&Vs[ni * 16 + r][32 + g * 8], oacc[ni], 0, 0, 0);
    }
  }
#undef LOADKV

  float linv[4];
#pragma unroll
  for (int j = 0; j < 4; ++j) linv[j] = 1.f / __shfl(lrow, g * 4 + j);

#pragma unroll
  for (int ni = 0; ni < 4; ++ni)
#pragma unroll
    for (int j = 0; j < 4; ++j) {
      int tq = q0 + wid * 16 + g * 4 + j;
      if (tq >= NT) continue;
      float val = oacc[ni][j] * linv[j];
      int col = h * 64 + ni * 16 + r;
      if (tq < NX)
        ox[(size_t)(b * NX + tq) * DD + col] = f2bf(val);
      else
        oc[(size_t)(b * NC + tq - NX) * DD + col] = f2bf(val);
    }
}

extern "C" void kernel_launch(void* const* d_in, const int* in_sizes, int n_in,
                              void* d_out, int out_size, void* d_ws, size_t ws_size,
                              hipStream_t stream) {
  const float* x = (const float*)d_in[0];
  const float* c = (const float*)d_in[1];
  const float* vec = (const float*)d_in[2];
  const float* w_mod = (const float*)d_in[3];
  const float* b_mod = (const float*)d_in[4];
  const float* w_qkv_x = (const float*)d_in[5];
  const float* b_qkv_x = (const float*)d_in[6];
  const float* w_qkv_c = (const float*)d_in[7];
  const float* b_qkv_c = (const float*)d_in[8];
  const float* w_proj_x = (const float*)d_in[9];
  const float* b_proj_x = (const float*)d_in[10];
  const float* w_proj_c = (const float*)d_in[11];
  const float* b_proj_c = (const float*)d_in[12];
  const float* w1_x = (const float*)d_in[13];
  const float* b1_x = (const float*)d_in[14];
  const float* w2_x = (const float*)d_in[15];
  const float* b2_x = (const float*)d_in[16];
  const float* w1_c = (const float*)d_in[17];
  const float* b1_c = (const float*)d_in[18];
  const float* w2_c = (const float*)d_in[19];
  const float* b2_c = (const float*)d_in[20];

  if (ws_size < 229195776ull) return;  // workspace layout below needs this much

  char* ws = (char*)d_ws;
  // persistent: bf16-transposed weights + mod
  u16* wt_qkv_x = (u16*)(ws + 0);
  u16* wt_qkv_c = (u16*)(ws + 14155776);
  u16* wt_proj_x = (u16*)(ws + 28311552);
  u16* wt_proj_c = (u16*)(ws + 33030144);
  u16* wt_w1_x = (u16*)(ws + 37748736);
  u16* wt_w1_c = (u16*)(ws + 56623104);
  u16* wt_w2_x = (u16*)(ws + 75497472);
  u16* wt_w2_c = (u16*)(ws + 94371840);
  float* modf = (float*)(ws + 113246208);
  char* S = ws + 113393664;
  // slot 1 (14,475,264 B): x_n/c_n -> o_x/o_c -> xln/cln -> pb0 + pc0
  u16* xn = (u16*)(S);
  u16* cn = (u16*)(S + 12582912);
  // slot 2 (43,425,792 B): x2/c2 (f32); pb1 follows, then pc1 gap
  float* x2 = (float*)(S + 14475264);   // 25,165,824 B, ends S+39,641,088
  float* c2 = (float*)(S + 39641088);   //  3,784,704 B, ends S+43,425,792
  u16* pb0 = (u16*)(S);                 // 12,582,912 B (xn dead after mlp1 reads)
  u16* pc0 = (u16*)(S + 12582912);      //  1,892,352 B (cn dead after mlp1 reads)
  u16* pb1 = (u16*)(S + 43425792);      // 12,582,912 B (dead region after c2)
  u16* pc1 = (u16*)(S + 56008704);      //  1,892,352 B (gap before slot 3)
  const int PSTRIDE = 43425792 / 2;     // u16 stride pb0->pb1 AND pc0->pc1
  // slot 3 (57,901,056 B): q/k/vt -> h_x/h_c ; head also used as k_mod partials
  u16* qb = (u16*)(S + 57901056);
  u16* kb = (u16*)(S + 72376320);
  u16* vtb = (u16*)(S + 86851584);
  u16* hx = (u16*)(S + 57901056);
  u16* hc = (u16*)(S + 108232704);
  float* modpart = (float*)(S + 57901056);  // dead before q/k/vt written

  // 1) all 8 weight transposes in one dispatch
  {
    TDesc d;
    const float* Ws[8] = {w_qkv_x, w_qkv_c, w_proj_x, w_proj_c, w1_x, w1_c, w2_x, w2_c};
    u16* Wts[8] = {wt_qkv_x, wt_qkv_c, wt_proj_x, wt_proj_c, wt_w1_x, wt_w1_c, wt_w2_x, wt_w2_c};
    int Ks[8] = {DD, DD, DD, DD, DD, DD, MHD, MHD};
    int Ns[8] = {NQKV, NQKV, DD, DD, MHD, MHD, DD, DD};
    int off = 0;
    for (int i = 0; i < 8; ++i) {
      d.W[i] = Ws[i]; d.Wt[i] = Wts[i]; d.K[i] = Ks[i]; d.N[i] = Ns[i];
      d.off[i] = off;
      off += (Ns[i] >> 5) * (Ks[i] >> 5);
    }
    d.off[8] = off;
    k_transpose8<<<dim3(off), 256, 0, stream>>>(d);
  }

  // 2) modulation vector (split-K, deterministic two-stage)
  k_mod_part<<<dim3(NMOD / 256, KSPL), 256, 0, stream>>>(vec, w_mod, modpart);
  k_mod_red<<<dim3(NMOD / 256), 256, 0, stream>>>(modpart, b_mod, modf);

  // 3) modulated LN -> bf16
  k_ln<<<dim3(BB * NX), 256, 0, stream>>>(x, xn, modf, 0, DD, NX);
  k_ln<<<dim3(BB * NC), 256, 0, stream>>>(c, cn, modf, 3 * DD, 4 * DD, NC);

  // 4) merged QKV GEMM (x+c) with scatter epilogue -> qb,kb,vtb directly
  k_gemm2<5, 5><<<dim3(NQKV / 128, 37), 256, 0, stream>>>(
      xn, wt_qkv_x, b_qkv_x, BB * NX, NX, 0, DD,
      cn, wt_qkv_c, b_qkv_c, BB * NC, NC, NX, DD,
      32, NQKV, DD, DD, 0, nullptr, nullptr, nullptr, nullptr, nullptr,
      qb, kb, vtb);

  // 5) flash attention (QBLK=128, 8 waves) -> o (written into slot 1)
  k_attn<<<dim3((NT + 127) / 128, HH, BB), 512, 0, stream>>>(qb, kb, vtb, xn, cn);

  // 6) merged output projections with gated residual -> x2/c2 f32
  k_gemm2<2, 2><<<dim3(DD / 128, 37), 256, 0, stream>>>(
      xn, wt_proj_x, b_proj_x, BB * NX, NX, 2 * DD, DD,
      cn, wt_proj_c, b_proj_c, BB * NC, NC, 5 * DD, DD,
      32, DD, DD, DD, 0, x2, c2, x, c, modf, nullptr, nullptr, nullptr);

  // 7) plain LN -> bf16
  k_ln<<<dim3(BB * NX), 256, 0, stream>>>(x2, xn, nullptr, 0, 0, NX);
  k_ln<<<dim3(BB * NC), 256, 0, stream>>>(c2, cn, nullptr, 0, 0, NC);

  // 8) merged MLP-1 (gelu) -> hx/hc
  k_gemm2<1, 1><<<dim3(MHD / 128, 37), 256, 0, stream>>>(
      xn, wt_w1_x, b1_x, BB * NX, NX, 0, DD,
      cn, wt_w1_c, b1_c, BB * NC, NC, 0, DD,
      32, MHD, DD, DD, 0, hx, hc, nullptr, nullptr, nullptr, nullptr, nullptr, nullptr);

  float* outx = (float*)d_out;
  float* outc = outx + (size_t)BB * NX * DD;
  // 9) merged MLP-2: BOTH streams split-K over z (96 K-steps every block)
  k_gemm2<4, 4><<<dim3(DD / 128, 37, 2), 256, 0, stream>>>(
      hx, wt_w2_x, b2_x, BB * NX, NX, PSTRIDE, MHD / 2,
      hc, wt_w2_c, b2_c, BB * NC, NC, PSTRIDE, MHD / 2,
      32, DD, MHD, MHD, MHD / 2, pb0, pc0, nullptr, nullptr, nullptr,
      nullptr, nullptr, nullptr);
  k_red2<<<dim3(BB * (NX + NC)), 256, 0, stream>>>(
      pb0, pb1, x2, b2_x, pc0, pc1, c2, b2_c, outx, outc);
}

// Round 12
// 674.645 us; speedup vs baseline: 3.6857x; 1.0212x over previous
//
#include <hip/hip_runtime.h>
#include <stdint.h>

typedef unsigned short u16;
typedef unsigned int u32;
typedef __attribute__((ext_vector_type(8))) short bf16x8;
typedef __attribute__((ext_vector_type(8))) unsigned short u16x8;
typedef __attribute__((ext_vector_type(2))) unsigned int u32x2;
typedef __attribute__((ext_vector_type(4))) float f32x4;

#define LB256 __launch_bounds__(256, 2)

// ---- problem dims ----
#define BB 4
#define NX 1024
#define NC 154
#define NT 1178
#define NTP 1184   // padded t stride for V^T (16B-aligned rows)
#define DD 1536
#define HH 24
#define MHD 6144
#define NQKV 4608
#define NMOD 9216
#define KSPL 6

__device__ __forceinline__ int imin(int a, int b) { return a < b ? a : b; }

__device__ __forceinline__ u16 f2bf(float f) {
  u32 u = __float_as_uint(f);
  u32 r = (u + 0x7fffu + ((u >> 16) & 1u)) >> 16;
  return (u16)r;
}

__device__ __forceinline__ float bf2f(u16 v) {
  u32 u = ((u32)v) << 16;
  return __uint_as_float(u);
}

// tanh-gelu via sigmoid identity: 0.5x(1+tanh(z)) == x * sigmoid(2z)
__device__ __forceinline__ float gelu_t(float x) {
  float u = 1.5957691216f * x * fmaf(0.044715f, x * x, 1.f);
  return x / (1.f + __expf(-u));
}

__device__ __forceinline__ f32x4 fzero4() {
  f32x4 z; z[0] = 0.f; z[1] = 0.f; z[2] = 0.f; z[3] = 0.f; return z;
}

// async global->LDS, 16B per lane; LDS dest = wave-uniform base + lane*16
__device__ __forceinline__ void glds16(const u16* g, u16* l) {
  __builtin_amdgcn_global_load_lds(
      (const __attribute__((address_space(1))) void*)g,
      (__attribute__((address_space(3))) void*)l, 16, 0, 0);
}

#define WAITV4 asm volatile("s_waitcnt vmcnt(4)" ::: "memory")
#define WAITV0 asm volatile("s_waitcnt vmcnt(0)" ::: "memory")
#define SCHEDB __builtin_amdgcn_sched_barrier(0)

// ---- batched weight transpose + f32->bf16: 8 matrices, one dispatch ----
// float2 loads, packed-u32 bf16 stores (G13).
struct TDesc {
  const float* W[8];
  u16* Wt[8];
  int K[8];
  int N[8];
  int off[9];  // prefix block offsets
};

__global__ void k_transpose8(TDesc d) {
  __shared__ float tile[32][33];
  int bid = blockIdx.x;
  int i = 0;
#pragma unroll
  for (int t = 1; t < 8; ++t)
    if (bid >= d.off[t]) i = t;
  const float* W = d.W[i];
  u16* Wt = d.Wt[i];
  const int K = d.K[i], N = d.N[i];
  const int local = bid - d.off[i];
  const int nbx = N >> 5;
  const int n0 = (local % nbx) * 32, k0 = (local / nbx) * 32;
  const int cx = threadIdx.x & 15, ry = threadIdx.x >> 4;  // 16 x 16
#pragma unroll
  for (int j = 0; j < 32; j += 16) {
    float2 t2 = *(const float2*)&W[(size_t)(k0 + ry + j) * N + n0 + cx * 2];
    tile[ry + j][cx * 2] = t2.x;
    tile[ry + j][cx * 2 + 1] = t2.y;
  }
  __syncthreads();
#pragma unroll
  for (int j = 0; j < 32; j += 16) {
    const int ny = ry + j;
    u32 w = (u32)f2bf(tile[cx * 2][ny]) | ((u32)f2bf(tile[cx * 2 + 1][ny]) << 16);
    *(u32*)&Wt[(size_t)(n0 + ny) * K + k0 + cx * 2] = w;
  }
}

// ---- mod = silu(vec) @ w_mod + b_mod : split-K partials (deterministic) ----
__global__ void k_mod_part(const float* __restrict__ vec, const float* __restrict__ w_mod,
                           float* __restrict__ part) {
  __shared__ float sv[BB][256];
  int n = blockIdx.x * 256 + threadIdx.x;
  int kb = blockIdx.y;
  int k0 = kb * 256;
  for (int i = threadIdx.x; i < BB * 256; i += 256) {
    int b = i >> 8, kk = i & 255;
    float v = vec[b * DD + k0 + kk];
    sv[b][kk] = v / (1.f + __expf(-v));
  }
  __syncthreads();
  float a0 = 0.f, a1 = 0.f, a2 = 0.f, a3 = 0.f;
  for (int k = 0; k < 256; ++k) {
    float w = w_mod[(size_t)(k0 + k) * NMOD + n];
    a0 = fmaf(sv[0][k], w, a0);
    a1 = fmaf(sv[1][k], w, a1);
    a2 = fmaf(sv[2][k], w, a2);
    a3 = fmaf(sv[3][k], w, a3);
  }
  part[((size_t)kb * BB + 0) * NMOD + n] = a0;
  part[((size_t)kb * BB + 1) * NMOD + n] = a1;
  part[((size_t)kb * BB + 2) * NMOD + n] = a2;
  part[((size_t)kb * BB + 3) * NMOD + n] = a3;
}

__global__ void k_mod_red(const float* __restrict__ part, const float* __restrict__ b_mod,
                          float* __restrict__ mod) {
  int n = blockIdx.x * 256 + threadIdx.x;
  float bb = b_mod[n];
#pragma unroll
  for (int b = 0; b < BB; ++b) {
    float s = bb;
#pragma unroll
    for (int kb = 0; kb < KSPL; ++kb) s += part[((size_t)kb * BB + b) * NMOD + n];
    mod[b * NMOD + n] = s;
  }
}

// ---- LayerNorm (optionally modulated) f32 -> bf16, float2-vectorized ----
__global__ LB256 void k_ln(const float* __restrict__ in, u16* __restrict__ out,
                           const float* __restrict__ modp, int sh_off, int sc_off,
                           int rows_per_b) {
  int row = blockIdx.x;
  int b = row / rows_per_b;
  const float2* xr = (const float2*)(in + (size_t)row * DD);
  float2 v[3];
  float s = 0.f, s2 = 0.f;
#pragma unroll
  for (int i = 0; i < 3; ++i) {
    float2 t = xr[threadIdx.x + 256 * i];
    v[i] = t;
    s += t.x + t.y;
    s2 += t.x * t.x + t.y * t.y;
  }
#pragma unroll
  for (int m = 32; m >= 1; m >>= 1) {
    s += __shfl_xor(s, m);
    s2 += __shfl_xor(s2, m);
  }
  __shared__ float red[8];
  int wid = threadIdx.x >> 6;
  if ((threadIdx.x & 63) == 0) { red[wid] = s; red[4 + wid] = s2; }
  __syncthreads();
  s = red[0] + red[1] + red[2] + red[3];
  s2 = red[4] + red[5] + red[6] + red[7];
  float mean = s * (1.f / (float)DD);
  float var = s2 * (1.f / (float)DD) - mean * mean;
  float rstd = rsqrtf(var + 1e-6f);
#pragma unroll
  for (int i = 0; i < 3; ++i) {
    int d = (threadIdx.x + 256 * i) * 2;
    float y0 = (v[i].x - mean) * rstd;
    float y1 = (v[i].y - mean) * rstd;
    if (modp) {
      float2 sc = *(const float2*)&modp[b * NMOD + sc_off + d];
      float2 sh = *(const float2*)&modp[b * NMOD + sh_off + d];
      y0 = y0 * (1.f + sc.x) + sh.x;
      y1 = y1 * (1.f + sc.y) + sh.y;
    }
    u32 w = (u32)f2bf(y0) | ((u32)f2bf(y1) << 16);
    *(u32*)&out[(size_t)row * DD + d] = w;
  }
}

// ---- GEMM epilogue variants ----
// 0 bias->bf16 | 1 gelu->bf16 | 2 resid+g*(acc+bias)->f32 | 3 resid+acc+bias->f32
// 4 acc->bf16 partial at outp + zed*goff | 5 qkv scatter (q,k (b,h,t,d); v^T)
template <int EPI>
__device__ __forceinline__ void gemm_epi(
    const f32x4 (&acc)[4][4], int m0, int n0, int wm, int wn, int g, int r,
    int M, int N, const float* bias, void* outp, const float* resid,
    const float* modp, int goff, int rpb, int zed,
    u16* qb, u16* kb, u16* vtb) {
#pragma unroll
  for (int mi = 0; mi < 4; ++mi) {
#pragma unroll
    for (int ni = 0; ni < 4; ++ni) {
      const int col = n0 + wn + ni * 16 + r;
      float bv = 0.f;
      if constexpr (EPI != 4) bv = bias[col];
#pragma unroll
      for (int j = 0; j < 4; ++j) {
        const int row = m0 + wm + mi * 16 + g * 4 + j;
        if (row >= M) continue;
        const size_t off = (size_t)row * N + col;
        float v = acc[mi][ni][j] + bv;
        if constexpr (EPI == 0) {
          ((u16*)outp)[off] = f2bf(v);
        } else if constexpr (EPI == 1) {
          ((u16*)outp)[off] = f2bf(gelu_t(v));
        } else if constexpr (EPI == 2) {
          const int b = row / rpb;
          ((float*)outp)[off] = resid[off] + modp[b * NMOD + goff + col] * v;
        } else if constexpr (EPI == 3) {
          ((float*)outp)[off] = resid[off] + v;
        } else if constexpr (EPI == 4) {
          ((u16*)outp)[(size_t)zed * (size_t)goff + off] = f2bf(acc[mi][ni][j]);
        } else {  // 5: qkv scatter; block's 128-col span is purely q, k, or v
          const int b = row / rpb;
          const int t = goff + (row - b * rpb);
          const u16 bw = f2bf(v);
          if (col < DD) {
            const int h = col >> 6, d = col & 63;
            qb[(((size_t)b * HH + h) * NT + t) * 64 + d] = bw;
          } else if (col < 2 * DD) {
            const int cc = col - DD;
            const int h = cc >> 6, d = cc & 63;
            kb[(((size_t)b * HH + h) * NT + t) * 64 + d] = bw;
          } else {
            const int cc = col - 2 * DD;
            const int h = cc >> 6, d = cc & 63;
            vtb[((size_t)b * HH + h) * (64 * NTP) + (size_t)d * NTP + t] = bw;
          }
        }
      }
    }
  }
}

// ---- merged dual-stream pipelined bf16 MFMA GEMM, 128x128x32 tile ----
// Role 1 (m-blocks [0,yHi)) uses arg-set 1 / EPI1; role 2 uses set 2 / EPI2.
// blockIdx.z split-K (kzOff element offset) applies to BOTH roles.
// Panel-major rasterization (8-wide n-panels, m-fast) keeps each XCD chunk's
// B working-set ~3 MB (L2-resident) instead of streaming the full B row.
// 3-buffer LDS, counted vmcnt(4), one barrier per K-step, XOR-swizzled LDS.
template <int EPI1, int EPI2>
__global__ LB256 void k_gemm2(
    const u16* __restrict__ A1, const u16* __restrict__ Bt1, const float* __restrict__ bias1,
    int M1, int rpb1, int goff1, int kLen1,
    const u16* __restrict__ A2, const u16* __restrict__ Bt2, const float* __restrict__ bias2,
    int M2, int rpb2, int goff2, int kLen2,
    int yHi, int N, int lda, int ldb, int kzOff,
    void* __restrict__ out1, void* __restrict__ out2,
    const float* __restrict__ resid1, const float* __restrict__ resid2,
    const float* __restrict__ modp,
    u16* __restrict__ qb, u16* __restrict__ kb, u16* __restrict__ vtb) {
  __shared__ __align__(16) u16 sm[3 * 8192];  // 48 KB
  const int tid = threadIdx.x;
  const int lane = tid & 63;
  const int g = lane >> 4, r = lane & 15;
  const int wid = tid >> 6;

  // bijective XCD-aware tile remap (m204) over the full (gx x gyTot) grid
  const int gx = gridDim.x;
  const int gyTot = gridDim.y;
  const int nwg = gx * gyTot;
  int wg = blockIdx.y * gx + blockIdx.x;
  {
    int q = nwg >> 3, rr = nwg & 7;
    int xcd = wg & 7, sl = wg >> 3;
    wg = (xcd < rr ? xcd * (q + 1) : rr * (q + 1) + (xcd - rr) * q) + sl;
  }
  // panel-major (8-wide n-panels, m-fast within panel), bijective for any gx
  int mIdx, nIdx;
  {
    const int np1 = (gx - 1) >> 3;       // number of full 8-wide panels
    const int lastw = gx - np1 * 8;      // width of last panel (1..8)
    const int full = gyTot * 8;
    if (wg < np1 * full) {
      int p = wg / full, off = wg % full;
      mIdx = off >> 3;
      nIdx = p * 8 + (off & 7);
    } else {
      int off = wg - np1 * full;
      mIdx = off / lastw;
      nIdx = np1 * 8 + off % lastw;
    }
  }
  const bool role2 = mIdx >= yHi;

  const u16* A = role2 ? A2 : A1;
  const u16* Bt = role2 ? Bt2 : Bt1;
  const int M = role2 ? M2 : M1;
  const int kLen = role2 ? kLen2 : kLen1;
  const int m0 = (role2 ? (mIdx - yHi) : mIdx) * 128, n0 = nIdx * 128;
  const int wm = (wid >> 1) * 64, wn = (wid & 1) * 64;
  A += (size_t)blockIdx.z * kzOff;
  Bt += (size_t)blockIdx.z * kzOff;

  f32x4 acc[4][4];
#pragma unroll
  for (int i = 0; i < 4; ++i)
#pragma unroll
    for (int j = 0; j < 4; ++j) acc[i][j] = fzero4();

  // staging geometry (proven, 0 bank conflicts): wave wid owns chunks c0,c1;
  // lane l -> row c*16 + l/4, phys slot l&3 holds logical slot (l&3)^((l>>3)&3)
  const int rl = lane >> 2;
  const int slg = (lane & 3) ^ ((lane >> 3) & 3);
  const int c0 = wid * 2, c1 = wid * 2 + 1;
  const size_t aR0 = (size_t)imin(m0 + c0 * 16 + rl, M - 1) * lda + slg * 8;
  const size_t aR1 = (size_t)imin(m0 + c1 * 16 + rl, M - 1) * lda + slg * 8;
  const size_t bR0 = (size_t)(n0 + c0 * 16 + rl) * ldb + slg * 8;
  const size_t bR1 = (size_t)(n0 + c1 * 16 + rl) * ldb + slg * 8;

  int aOff[4], bOff[4];
#pragma unroll
  for (int mi = 0; mi < 4; ++mi) aOff[mi] = (wm + mi * 16 + r) * 32 + ((g ^ ((r >> 1) & 3)) * 8);
#pragma unroll
  for (int ni = 0; ni < 4; ++ni) bOff[ni] = 4096 + (wn + ni * 16 + r) * 32 + ((g ^ ((r >> 1) & 3)) * 8);

  const int nt = kLen >> 5;  // K-steps of 32

#define STAGE(BI, T)                                        \
  do {                                                      \
    u16* bb = &sm[(BI) * 8192];                             \
    size_t kk = (size_t)(T) * 32;                           \
    glds16(A + aR0 + kk, bb + c0 * 512);                    \
    glds16(A + aR1 + kk, bb + c1 * 512);                    \
    glds16(Bt + bR0 + kk, bb + 4096 + c0 * 512);            \
    glds16(Bt + bR1 + kk, bb + 4096 + c1 * 512);            \
  } while (0)

  STAGE(0, 0);
  STAGE(1, 1);

  for (int t = 0; t < nt - 1; ++t) {
    WAITV4;                              // my tile-t loads landed (t+1 in flight)
    __builtin_amdgcn_s_barrier();        // all waves' tile-t data published
    SCHEDB;
    if (t + 2 < nt) STAGE((t + 2) % 3, t + 2);
    const u16* bb = &sm[(t % 3) * 8192];
    bf16x8 af[4], bfr[4];
#pragma unroll
    for (int mi = 0; mi < 4; ++mi) af[mi] = *(const bf16x8*)(bb + aOff[mi]);
#pragma unroll
    for (int ni = 0; ni < 4; ++ni) bfr[ni] = *(const bf16x8*)(bb + bOff[ni]);
    __builtin_amdgcn_s_setprio(1);
#pragma unroll
    for (int mi = 0; mi < 4; ++mi)
#pragma unroll
      for (int ni = 0; ni < 4; ++ni)
        acc[mi][ni] = __builtin_amdgcn_mfma_f32_16x16x32_bf16(af[mi], bfr[ni], acc[mi][ni], 0, 0, 0);
    __builtin_amdgcn_s_setprio(0);
    SCHEDB;
  }
  {
    WAITV0;
    __builtin_amdgcn_s_barrier();
    SCHEDB;
    const u16* bb = &sm[((nt - 1) % 3) * 8192];
    bf16x8 af[4], bfr[4];
#pragma unroll
    for (int mi = 0; mi < 4; ++mi) af[mi] = *(const bf16x8*)(bb + aOff[mi]);
#pragma unroll
    for (int ni = 0; ni < 4; ++ni) bfr[ni] = *(const bf16x8*)(bb + bOff[ni]);
#pragma unroll
    for (int mi = 0; mi < 4; ++mi)
#pragma unroll
      for (int ni = 0; ni < 4; ++ni)
        acc[mi][ni] = __builtin_amdgcn_mfma_f32_16x16x32_bf16(af[mi], bfr[ni], acc[mi][ni], 0, 0, 0);
  }
#undef STAGE

  if (role2)
    gemm_epi<EPI2>(acc, m0, n0, wm, wn, g, r, M, N, bias2, out2, resid2, modp,
                   goff2, rpb2, blockIdx.z, qb, kb, vtb);
  else
    gemm_epi<EPI1>(acc, m0, n0, wm, wn, g, r, M, N, bias1, out1, resid1, modp,
                   goff1, rpb1, blockIdx.z, qb, kb, vtb);
}

// ---- split-K reduce for mlp2 (x rows then c rows) ----
__global__ void k_red2(const u16* __restrict__ p0x, const u16* __restrict__ p1x,
                       const float* __restrict__ residx, const float* __restrict__ bx,
                       const u16* __restrict__ p0c, const u16* __restrict__ p1c,
                       const float* __restrict__ residc, const float* __restrict__ bc,
                       float* __restrict__ outx, float* __restrict__ outc) {
  int row = blockIdx.x;
  if (row < BB * NX) {
    size_t base = (size_t)row * DD;
#pragma unroll
    for (int i = 0; i < 6; ++i) {
      int j = threadIdx.x + 256 * i;
      outx[base + j] = residx[base + j] + bx[j] + bf2f(p0x[base + j]) + bf2f(p1x[base + j]);
    }
  } else {
    size_t base = (size_t)(row - BB * NX) * DD;
#pragma unroll
    for (int i = 0; i < 6; ++i) {
      int j = threadIdx.x + 256 * i;
      outc[base + j] = residc[base + j] + bc[j] + bf2f(p0c[base + j]) + bf2f(p1c[base + j]);
    }
  }
}

// ---- flash attention: QBLK=128 (8 waves x 16 rows), KBLK=64, HD=64 ----
// Swapped QK^T (S^T = mfma(K,Q)): lane owns q-row (lane&15), 16 in-lane t.
// In-register softmax, packed b64 P-writes, next-tile K/V register prefetch.
__global__ __launch_bounds__(512, 2) void k_attn(
    const u16* __restrict__ q, const u16* __restrict__ kk,
    const u16* __restrict__ vt, u16* __restrict__ ox, u16* __restrict__ oc) {
  __shared__ __align__(16) u16 Ks[64][72];
  __shared__ __align__(16) u16 Vs[64][72];
  __shared__ __align__(16) u16 Ps[8][16][72];

  const int lane = threadIdx.x & 63, wid = threadIdx.x >> 6;  // wid 0..7
  const int g = lane >> 4, r = lane & 15;
  const int q0 = blockIdx.x * 128;
  const int h = blockIdx.y, b = blockIdx.z;
  const size_t bh = (size_t)b * HH + h;
  const u16* qp = q + bh * (NT * 64);
  const u16* kp = kk + bh * (NT * 64);
  const u16* vp = vt + bh * (64 * NTP);

  const int qrow = imin(q0 + wid * 16 + r, NT - 1);
  u16x8 qr0 = *(const u16x8*)(qp + (size_t)qrow * 64 + g * 8);
  u16x8 qr1 = *(const u16x8*)(qp + (size_t)qrow * 64 + 32 + g * 8);
  bf16x8 qa0, qa1;
#pragma unroll
  for (int e = 0; e < 8; ++e) {
    qa0[e] = (short)f2bf(bf2f(qr0[e]) * 0.125f);
    qa1[e] = (short)f2bf(bf2f(qr1[e]) * 0.125f);
  }

  f32x4 oacc[4];
#pragma unroll
  for (int i = 0; i < 4; ++i) oacc[i] = fzero4();
  float mrow = -1e30f, lrow = 0.f;

  const int trA = threadIdx.x >> 3;
  const int ccA = (threadIdx.x & 7) * 8;

  u16x8 kreg, vreg;
#define LOADKV(T0)                                                     \
  do {                                                                 \
    int tsrc = imin((T0) + trA, NT - 1);                               \
    kreg = *(const u16x8*)(kp + (size_t)tsrc * 64 + ccA);              \
    int tcol = (T0) + ccA;                                             \
    if (tcol + 8 <= NT) {                                              \
      vreg = *(const u16x8*)(vp + (size_t)trA * NTP + tcol);           \
    } else {                                                           \
      _Pragma("unroll")                                                \
      for (int e = 0; e < 8; ++e)                                      \
        vreg[e] = vp[(size_t)trA * NTP + imin(tcol + e, NT - 1)];      \
    }                                                                  \
  } while (0)

  LOADKV(0);

  for (int t0 = 0; t0 < NT; t0 += 64) {
    if (t0) __syncthreads();
    *(u16x8*)&Ks[trA][ccA] = kreg;
    *(u16x8*)&Vs[trA][ccA] = vreg;
    __syncthreads();
    if (t0 + 64 < NT) LOADKV(t0 + 64);

    f32x4 s[4];
#pragma unroll
    for (int ni = 0; ni < 4; ++ni) {
      s[ni] = fzero4();
      s[ni] = __builtin_amdgcn_mfma_f32_16x16x32_bf16(*(const bf16x8*)&Ks[ni * 16 + r][g * 8], qa0, s[ni], 0, 0, 0);
      s[ni] = __builtin_amdgcn_mfma_f32_16x16x32_bf16(*(const bf16x8*)&Ks[ni * 16 + r][32 + g * 8], qa1, s[ni], 0, 0, 0);
    }

    float pv[4][4];
    float pm = -1e30f;
#pragma unroll
    for (int ni = 0; ni < 4; ++ni)
#pragma unroll
      for (int j = 0; j < 4; ++j) {
        int t = t0 + ni * 16 + g * 4 + j;
        float sv = (t < NT) ? s[ni][j] : -1e30f;
        pv[ni][j] = sv;
        pm = fmaxf(pm, sv);
      }
    pm = fmaxf(pm, __shfl_xor(pm, 16));
    pm = fmaxf(pm, __shfl_xor(pm, 32));

    float mn = fmaxf(mrow, pm);
    float alpha = __expf(mrow - mn);
    mrow = mn;
    float rs = 0.f;
#pragma unroll
    for (int ni = 0; ni < 4; ++ni)
#pragma unroll
      for (int j = 0; j < 4; ++j) {
        float p = __expf(pv[ni][j] - mn);
        pv[ni][j] = p;
        rs += p;
      }
    rs += __shfl_xor(rs, 16);
    rs += __shfl_xor(rs, 32);
    lrow = lrow * alpha + rs;

#pragma unroll
    for (int j = 0; j < 4; ++j) {
      float aj = __shfl(alpha, g * 4 + j);
#pragma unroll
      for (int ni = 0; ni < 4; ++ni) oacc[ni][j] *= aj;
    }

#pragma unroll
    for (int ni = 0; ni < 4; ++ni) {
      u32x2 w;
      w[0] = (u32)f2bf(pv[ni][0]) | ((u32)f2bf(pv[ni][1]) << 16);
      w[1] = (u32)f2bf(pv[ni][2]) | ((u32)f2bf(pv[ni][3]) << 16);
      *(u32x2*)&Ps[wid][r][ni * 16 + g * 4] = w;
    }

    bf16x8 pa0 = *(const bf16x8*)&Ps[wid][r][g * 8];
    bf16x8 pa1 = *(const bf16x8*)&Ps[wid][r][32 + g * 8];
#pragma unroll
    for (int ni = 0; ni < 4; ++ni) {
      oacc[ni] = __builtin_amdgcn_mfma_f32_16x16x32_bf16(pa0, *(const bf16x8*)&Vs[ni * 16 + r][g * 8], oacc[ni], 0, 0, 0);
      oacc[ni] = __builtin_amdgcn_mfma_f32_16x16x32_bf16(pa1, *(const bf16x8*)&Vs[ni * 16 + r][32 + g * 8], oacc[ni], 0, 0, 0);
    }
  }
#undef LOADKV

  float linv[4];
#pragma unroll
  for (int j = 0; j < 4; ++j) linv[j] = 1.f / __shfl(lrow, g * 4 + j);

#pragma unroll
  for (int ni = 0; ni < 4; ++ni)
#pragma unroll
    for (int j = 0; j < 4; ++j) {
      int tq = q0 + wid * 16 + g * 4 + j;
      if (tq >= NT) continue;
      float val = oacc[ni][j] * linv[j];
      int col = h * 64 + ni * 16 + r;
      if (tq < NX)
        ox[(size_t)(b * NX + tq) * DD + col] = f2bf(val);
      else
        oc[(size_t)(b * NC + tq - NX) * DD + col] = f2bf(val);
    }
}

extern "C" void kernel_launch(void* const* d_in, const int* in_sizes, int n_in,
                              void* d_out, int out_size, void* d_ws, size_t ws_size,
                              hipStream_t stream) {
  const float* x = (const float*)d_in[0];
  const float* c = (const float*)d_in[1];
  const float* vec = (const float*)d_in[2];
  const float* w_mod = (const float*)d_in[3];
  const float* b_mod = (const float*)d_in[4];
  const float* w_qkv_x = (const float*)d_in[5];
  const float* b_qkv_x = (const float*)d_in[6];
  const float* w_qkv_c = (const float*)d_in[7];
  const float* b_qkv_c = (const float*)d_in[8];
  const float* w_proj_x = (const float*)d_in[9];
  const float* b_proj_x = (const float*)d_in[10];
  const float* w_proj_c = (const float*)d_in[11];
  const float* b_proj_c = (const float*)d_in[12];
  const float* w1_x = (const float*)d_in[13];
  const float* b1_x = (const float*)d_in[14];
  const float* w2_x = (const float*)d_in[15];
  const float* b2_x = (const float*)d_in[16];
  const float* w1_c = (const float*)d_in[17];
  const float* b1_c = (const float*)d_in[18];
  const float* w2_c = (const float*)d_in[19];
  const float* b2_c = (const float*)d_in[20];

  if (ws_size < 229195776ull) return;  // workspace layout below needs this much

  char* ws = (char*)d_ws;
  // persistent: bf16-transposed weights + mod
  u16* wt_qkv_x = (u16*)(ws + 0);
  u16* wt_qkv_c = (u16*)(ws + 14155776);
  u16* wt_proj_x = (u16*)(ws + 28311552);
  u16* wt_proj_c = (u16*)(ws + 33030144);
  u16* wt_w1_x = (u16*)(ws + 37748736);
  u16* wt_w1_c = (u16*)(ws + 56623104);
  u16* wt_w2_x = (u16*)(ws + 75497472);
  u16* wt_w2_c = (u16*)(ws + 94371840);
  float* modf = (float*)(ws + 113246208);
  char* S = ws + 113393664;
  // slot 1 (14,475,264 B): x_n/c_n -> o_x/o_c -> xln/cln -> pb0 + pc0
  u16* xn = (u16*)(S);
  u16* cn = (u16*)(S + 12582912);
  // slot 2 (43,425,792 B): x2/c2 (f32); pb1 follows, then pc1 gap
  float* x2 = (float*)(S + 14475264);   // 25,165,824 B, ends S+39,641,088
  float* c2 = (float*)(S + 39641088);   //  3,784,704 B, ends S+43,425,792
  u16* pb0 = (u16*)(S);                 // 12,582,912 B (xn dead after mlp1 reads)
  u16* pc0 = (u16*)(S + 12582912);      //  1,892,352 B (cn dead after mlp1 reads)
  u16* pb1 = (u16*)(S + 43425792);      // 12,582,912 B (dead region after c2)
  u16* pc1 = (u16*)(S + 56008704);      //  1,892,352 B (gap before slot 3)
  const int PSTRIDE = 43425792 / 2;     // u16 stride pb0->pb1 AND pc0->pc1
  // slot 3 (57,901,056 B): q/k/vt -> h_x/h_c ; head also used as k_mod partials
  u16* qb = (u16*)(S + 57901056);
  u16* kb = (u16*)(S + 72376320);
  u16* vtb = (u16*)(S + 86851584);
  u16* hx = (u16*)(S + 57901056);
  u16* hc = (u16*)(S + 108232704);
  float* modpart = (float*)(S + 57901056);  // dead before q/k/vt written

  // 1) all 8 weight transposes in one dispatch
  {
    TDesc d;
    const float* Ws[8] = {w_qkv_x, w_qkv_c, w_proj_x, w_proj_c, w1_x, w1_c, w2_x, w2_c};
    u16* Wts[8] = {wt_qkv_x, wt_qkv_c, wt_proj_x, wt_proj_c, wt_w1_x, wt_w1_c, wt_w2_x, wt_w2_c};
    int Ks[8] = {DD, DD, DD, DD, DD, DD, MHD, MHD};
    int Ns[8] = {NQKV, NQKV, DD, DD, MHD, MHD, DD, DD};
    int off = 0;
    for (int i = 0; i < 8; ++i) {
      d.W[i] = Ws[i]; d.Wt[i] = Wts[i]; d.K[i] = Ks[i]; d.N[i] = Ns[i];
      d.off[i] = off;
      off += (Ns[i] >> 5) * (Ks[i] >> 5);
    }
    d.off[8] = off;
    k_transpose8<<<dim3(off), 256, 0, stream>>>(d);
  }

  // 2) modulation vector (split-K, deterministic two-stage)
  k_mod_part<<<dim3(NMOD / 256, KSPL), 256, 0, stream>>>(vec, w_mod, modpart);
  k_mod_red<<<dim3(NMOD / 256), 256, 0, stream>>>(modpart, b_mod, modf);

  // 3) modulated LN -> bf16
  k_ln<<<dim3(BB * NX), 256, 0, stream>>>(x, xn, modf, 0, DD, NX);
  k_ln<<<dim3(BB * NC), 256, 0, stream>>>(c, cn, modf, 3 * DD, 4 * DD, NC);

  // 4) merged QKV GEMM (x+c) with scatter epilogue -> qb,kb,vtb directly
  k_gemm2<5, 5><<<dim3(NQKV / 128, 37), 256, 0, stream>>>(
      xn, wt_qkv_x, b_qkv_x, BB * NX, NX, 0, DD,
      cn, wt_qkv_c, b_qkv_c, BB * NC, NC, NX, DD,
      32, NQKV, DD, DD, 0, nullptr, nullptr, nullptr, nullptr, nullptr,
      qb, kb, vtb);

  // 5) flash attention (QBLK=128, 8 waves) -> o (written into slot 1)
  k_attn<<<dim3((NT + 127) / 128, HH, BB), 512, 0, stream>>>(qb, kb, vtb, xn, cn);

  // 6) merged output projections with gated residual -> x2/c2 f32
  k_gemm2<2, 2><<<dim3(DD / 128, 37), 256, 0, stream>>>(
      xn, wt_proj_x, b_proj_x, BB * NX, NX, 2 * DD, DD,
      cn, wt_proj_c, b_proj_c, BB * NC, NC, 5 * DD, DD,
      32, DD, DD, DD, 0, x2, c2, x, c, modf, nullptr, nullptr, nullptr);

  // 7) plain LN -> bf16
  k_ln<<<dim3(BB * NX), 256, 0, stream>>>(x2, xn, nullptr, 0, 0, NX);
  k_ln<<<dim3(BB * NC), 256, 0, stream>>>(c2, cn, nullptr, 0, 0, NC);

  // 8) merged MLP-1 (gelu) -> hx/hc
  k_gemm2<1, 1><<<dim3(MHD / 128, 37), 256, 0, stream>>>(
      xn, wt_w1_x, b1_x, BB * NX, NX, 0, DD,
      cn, wt_w1_c, b1_c, BB * NC, NC, 0, DD,
      32, MHD, DD, DD, 0, hx, hc, nullptr, nullptr, nullptr, nullptr, nullptr, nullptr);

  float* outx = (float*)d_out;
  float* outc = outx + (size_t)BB * NX * DD;
  // 9) merged MLP-2: BOTH streams split-K over z (96 K-steps every block)
  k_gemm2<4, 4><<<dim3(DD / 128, 37, 2), 256, 0, stream>>>(
      hx, wt_w2_x, b2_x, BB * NX, NX, PSTRIDE, MHD / 2,
      hc, wt_w2_c, b2_c, BB * NC, NC, PSTRIDE, MHD / 2,
      32, DD, MHD, MHD, MHD / 2, pb0, pc0, nullptr, nullptr, nullptr,
      nullptr, nullptr, nullptr);
  k_red2<<<dim3(BB * (NX + NC)), 256, 0, stream>>>(
      pb0, pb1, x2, b2_x, pc0, pc1, c2, b2_c, outx, outc);
}

// Round 13
// 656.044 us; speedup vs baseline: 3.7902x; 1.0284x over previous
//
#include <hip/hip_runtime.h>
#include <stdint.h>

typedef unsigned short u16;
typedef unsigned int u32;
typedef __attribute__((ext_vector_type(8))) short bf16x8;
typedef __attribute__((ext_vector_type(8))) unsigned short u16x8;
typedef __attribute__((ext_vector_type(2))) unsigned int u32x2;
typedef __attribute__((ext_vector_type(4))) float f32x4;

#define LB256 __launch_bounds__(256, 2)

// ---- problem dims ----
#define BB 4
#define NX 1024
#define NC 154
#define NT 1178
#define NTP 1184   // padded t stride for V^T (16B-aligned rows)
#define DD 1536
#define HH 24
#define MHD 6144
#define NQKV 4608
#define NMOD 9216
#define KSPL 6

__device__ __forceinline__ int imin(int a, int b) { return a < b ? a : b; }

__device__ __forceinline__ u16 f2bf(float f) {
  u32 u = __float_as_uint(f);
  u32 r = (u + 0x7fffu + ((u >> 16) & 1u)) >> 16;
  return (u16)r;
}

__device__ __forceinline__ float bf2f(u16 v) {
  u32 u = ((u32)v) << 16;
  return __uint_as_float(u);
}

// tanh-gelu via sigmoid identity: 0.5x(1+tanh(z)) == x * sigmoid(2z)
__device__ __forceinline__ float gelu_t(float x) {
  float u = 1.5957691216f * x * fmaf(0.044715f, x * x, 1.f);
  return x / (1.f + __expf(-u));
}

__device__ __forceinline__ f32x4 fzero4() {
  f32x4 z; z[0] = 0.f; z[1] = 0.f; z[2] = 0.f; z[3] = 0.f; return z;
}

// async global->LDS, 16B per lane; LDS dest = wave-uniform base + lane*16
__device__ __forceinline__ void glds16(const u16* g, u16* l) {
  __builtin_amdgcn_global_load_lds(
      (const __attribute__((address_space(1))) void*)g,
      (__attribute__((address_space(3))) void*)l, 16, 0, 0);
}

#define WAITV0 asm volatile("s_waitcnt vmcnt(0)" ::: "memory")
#define SCHEDB __builtin_amdgcn_sched_barrier(0)

// ---- batched weight transpose + f32->bf16: 8 matrices, one dispatch ----
// float2 loads, packed-u32 bf16 stores (G13).
struct TDesc {
  const float* W[8];
  u16* Wt[8];
  int K[8];
  int N[8];
  int off[9];  // prefix block offsets
};

__global__ void k_transpose8(TDesc d) {
  __shared__ float tile[32][33];
  int bid = blockIdx.x;
  int i = 0;
#pragma unroll
  for (int t = 1; t < 8; ++t)
    if (bid >= d.off[t]) i = t;
  const float* W = d.W[i];
  u16* Wt = d.Wt[i];
  const int K = d.K[i], N = d.N[i];
  const int local = bid - d.off[i];
  const int nbx = N >> 5;
  const int n0 = (local % nbx) * 32, k0 = (local / nbx) * 32;
  const int cx = threadIdx.x & 15, ry = threadIdx.x >> 4;  // 16 x 16
#pragma unroll
  for (int j = 0; j < 32; j += 16) {
    float2 t2 = *(const float2*)&W[(size_t)(k0 + ry + j) * N + n0 + cx * 2];
    tile[ry + j][cx * 2] = t2.x;
    tile[ry + j][cx * 2 + 1] = t2.y;
  }
  __syncthreads();
#pragma unroll
  for (int j = 0; j < 32; j += 16) {
    const int ny = ry + j;
    u32 w = (u32)f2bf(tile[cx * 2][ny]) | ((u32)f2bf(tile[cx * 2 + 1][ny]) << 16);
    *(u32*)&Wt[(size_t)(n0 + ny) * K + k0 + cx * 2] = w;
  }
}

// ---- mod = silu(vec) @ w_mod + b_mod : split-K partials (deterministic) ----
__global__ void k_mod_part(const float* __restrict__ vec, const float* __restrict__ w_mod,
                           float* __restrict__ part) {
  __shared__ float sv[BB][256];
  int n = blockIdx.x * 256 + threadIdx.x;
  int kb = blockIdx.y;
  int k0 = kb * 256;
  for (int i = threadIdx.x; i < BB * 256; i += 256) {
    int b = i >> 8, kk = i & 255;
    float v = vec[b * DD + k0 + kk];
    sv[b][kk] = v / (1.f + __expf(-v));
  }
  __syncthreads();
  float a0 = 0.f, a1 = 0.f, a2 = 0.f, a3 = 0.f;
  for (int k = 0; k < 256; ++k) {
    float w = w_mod[(size_t)(k0 + k) * NMOD + n];
    a0 = fmaf(sv[0][k], w, a0);
    a1 = fmaf(sv[1][k], w, a1);
    a2 = fmaf(sv[2][k], w, a2);
    a3 = fmaf(sv[3][k], w, a3);
  }
  part[((size_t)kb * BB + 0) * NMOD + n] = a0;
  part[((size_t)kb * BB + 1) * NMOD + n] = a1;
  part[((size_t)kb * BB + 2) * NMOD + n] = a2;
  part[((size_t)kb * BB + 3) * NMOD + n] = a3;
}

__global__ void k_mod_red(const float* __restrict__ part, const float* __restrict__ b_mod,
                          float* __restrict__ mod) {
  int n = blockIdx.x * 256 + threadIdx.x;
  float bb = b_mod[n];
#pragma unroll
  for (int b = 0; b < BB; ++b) {
    float s = bb;
#pragma unroll
    for (int kb = 0; kb < KSPL; ++kb) s += part[((size_t)kb * BB + b) * NMOD + n];
    mod[b * NMOD + n] = s;
  }
}

// ---- merged dual-stream LayerNorm f32 -> bf16, float2-vectorized ----
// rows [0, BB*NX) = stream 1; rest = stream 2. modp==nullptr -> plain LN.
__global__ LB256 void k_ln2(const float* __restrict__ in1, u16* __restrict__ out1,
                            const float* __restrict__ in2, u16* __restrict__ out2,
                            const float* __restrict__ modp, int sh1, int sc1,
                            int sh2, int sc2) {
  int row = blockIdx.x;
  const float* xr;
  u16* outp;
  int b, sh, sc;
  if (row < BB * NX) {
    xr = in1 + (size_t)row * DD;
    outp = out1 + (size_t)row * DD;
    b = row / NX; sh = sh1; sc = sc1;
  } else {
    int r2 = row - BB * NX;
    xr = in2 + (size_t)r2 * DD;
    outp = out2 + (size_t)r2 * DD;
    b = r2 / NC; sh = sh2; sc = sc2;
  }
  const float2* x2p = (const float2*)xr;
  float2 v[3];
  float s = 0.f, s2 = 0.f;
#pragma unroll
  for (int i = 0; i < 3; ++i) {
    float2 t = x2p[threadIdx.x + 256 * i];
    v[i] = t;
    s += t.x + t.y;
    s2 += t.x * t.x + t.y * t.y;
  }
#pragma unroll
  for (int m = 32; m >= 1; m >>= 1) {
    s += __shfl_xor(s, m);
    s2 += __shfl_xor(s2, m);
  }
  __shared__ float red[8];
  int wid = threadIdx.x >> 6;
  if ((threadIdx.x & 63) == 0) { red[wid] = s; red[4 + wid] = s2; }
  __syncthreads();
  s = red[0] + red[1] + red[2] + red[3];
  s2 = red[4] + red[5] + red[6] + red[7];
  float mean = s * (1.f / (float)DD);
  float var = s2 * (1.f / (float)DD) - mean * mean;
  float rstd = rsqrtf(var + 1e-6f);
#pragma unroll
  for (int i = 0; i < 3; ++i) {
    int d = (threadIdx.x + 256 * i) * 2;
    float y0 = (v[i].x - mean) * rstd;
    float y1 = (v[i].y - mean) * rstd;
    if (modp) {
      float2 scv = *(const float2*)&modp[b * NMOD + sc + d];
      float2 shv = *(const float2*)&modp[b * NMOD + sh + d];
      y0 = y0 * (1.f + scv.x) + shv.x;
      y1 = y1 * (1.f + scv.y) + shv.y;
    }
    u32 w = (u32)f2bf(y0) | ((u32)f2bf(y1) << 16);
    *(u32*)&outp[d] = w;
  }
}

// ---- GEMM epilogue variants ----
// 0 bias->bf16 | 1 gelu->bf16 | 2 resid+g*(acc+bias)->f32 | 3 resid+acc+bias->f32
// 4 acc->bf16 partial at outp + zed*goff | 5 qkv scatter (q,k (b,h,t,d); v^T)
template <int EPI>
__device__ __forceinline__ void gemm_epi(
    const f32x4 (&acc)[4][4], int m0, int n0, int wm, int wn, int g, int r,
    int M, int N, const float* bias, void* outp, const float* resid,
    const float* modp, int goff, int rpb, int zed,
    u16* qb, u16* kb, u16* vtb) {
#pragma unroll
  for (int mi = 0; mi < 4; ++mi) {
#pragma unroll
    for (int ni = 0; ni < 4; ++ni) {
      const int col = n0 + wn + ni * 16 + r;
      float bv = 0.f;
      if constexpr (EPI != 4) bv = bias[col];
#pragma unroll
      for (int j = 0; j < 4; ++j) {
        const int row = m0 + wm + mi * 16 + g * 4 + j;
        if (row >= M) continue;
        const size_t off = (size_t)row * N + col;
        float v = acc[mi][ni][j] + bv;
        if constexpr (EPI == 0) {
          ((u16*)outp)[off] = f2bf(v);
        } else if constexpr (EPI == 1) {
          ((u16*)outp)[off] = f2bf(gelu_t(v));
        } else if constexpr (EPI == 2) {
          const int b = row / rpb;
          ((float*)outp)[off] = resid[off] + modp[b * NMOD + goff + col] * v;
        } else if constexpr (EPI == 3) {
          ((float*)outp)[off] = resid[off] + v;
        } else if constexpr (EPI == 4) {
          ((u16*)outp)[(size_t)zed * (size_t)goff + off] = f2bf(acc[mi][ni][j]);
        } else {  // 5: qkv scatter; block's 128-col span is purely q, k, or v
          const int b = row / rpb;
          const int t = goff + (row - b * rpb);
          const u16 bw = f2bf(v);
          if (col < DD) {
            const int h = col >> 6, d = col & 63;
            qb[(((size_t)b * HH + h) * NT + t) * 64 + d] = bw;
          } else if (col < 2 * DD) {
            const int cc = col - DD;
            const int h = cc >> 6, d = cc & 63;
            kb[(((size_t)b * HH + h) * NT + t) * 64 + d] = bw;
          } else {
            const int cc = col - 2 * DD;
            const int h = cc >> 6, d = cc & 63;
            vtb[((size_t)b * HH + h) * (64 * NTP) + (size_t)d * NTP + t] = bw;
          }
        }
      }
    }
  }
}

// ---- merged dual-stream pipelined bf16 MFMA GEMM, 128x128 tile, BK=64 ----
// Role 1 (m-blocks [0,yHi)) uses arg-set 1 / EPI1; role 2 uses set 2 / EPI2.
// blockIdx.z split-K (kzOff element offset) applies to BOTH roles.
// Panel-major rasterization (8-wide n-panels, m-fast) keeps each XCD chunk's
// B working-set ~3 MB (L2-resident). 2 x 32KB LDS double-buffer; ONE barrier +
// ONE vmcnt drain per 64-deep K-tile (32 MFMAs amortize each sync).
// Requires kLen % 64 == 0.
template <int EPI1, int EPI2>
__global__ LB256 void k_gemm2(
    const u16* __restrict__ A1, const u16* __restrict__ Bt1, const float* __restrict__ bias1,
    int M1, int rpb1, int goff1, int kLen1,
    const u16* __restrict__ A2, const u16* __restrict__ Bt2, const float* __restrict__ bias2,
    int M2, int rpb2, int goff2, int kLen2,
    int yHi, int N, int lda, int ldb, int kzOff,
    void* __restrict__ out1, void* __restrict__ out2,
    const float* __restrict__ resid1, const float* __restrict__ resid2,
    const float* __restrict__ modp,
    u16* __restrict__ qb, u16* __restrict__ kb, u16* __restrict__ vtb) {
  __shared__ __align__(16) u16 sm[2 * 16384];  // 2 bufs x [A0|B0|A1|B1] = 64 KB
  const int tid = threadIdx.x;
  const int lane = tid & 63;
  const int g = lane >> 4, r = lane & 15;
  const int wid = tid >> 6;

  // bijective XCD-aware tile remap (m204) over the full (gx x gyTot) grid
  const int gx = gridDim.x;
  const int gyTot = gridDim.y;
  const int nwg = gx * gyTot;
  int wg = blockIdx.y * gx + blockIdx.x;
  {
    int q = nwg >> 3, rr = nwg & 7;
    int xcd = wg & 7, sl = wg >> 3;
    wg = (xcd < rr ? xcd * (q + 1) : rr * (q + 1) + (xcd - rr) * q) + sl;
  }
  // panel-major (8-wide n-panels, m-fast within panel), bijective for any gx
  int mIdx, nIdx;
  {
    const int np1 = (gx - 1) >> 3;       // number of full 8-wide panels
    const int lastw = gx - np1 * 8;      // width of last panel (1..8)
    const int full = gyTot * 8;
    if (wg < np1 * full) {
      int p = wg / full, off = wg % full;
      mIdx = off >> 3;
      nIdx = p * 8 + (off & 7);
    } else {
      int off = wg - np1 * full;
      mIdx = off / lastw;
      nIdx = np1 * 8 + off % lastw;
    }
  }
  const bool role2 = mIdx >= yHi;

  const u16* A = role2 ? A2 : A1;
  const u16* Bt = role2 ? Bt2 : Bt1;
  const int M = role2 ? M2 : M1;
  const int kLen = role2 ? kLen2 : kLen1;
  const int m0 = (role2 ? (mIdx - yHi) : mIdx) * 128, n0 = nIdx * 128;
  const int wm = (wid >> 1) * 64, wn = (wid & 1) * 64;
  A += (size_t)blockIdx.z * kzOff;
  Bt += (size_t)blockIdx.z * kzOff;

  f32x4 acc[4][4];
#pragma unroll
  for (int i = 0; i < 4; ++i)
#pragma unroll
    for (int j = 0; j < 4; ++j) acc[i][j] = fzero4();

  // staging geometry (proven, 0 bank conflicts): wave wid owns chunks c0,c1;
  // lane l -> row c*16 + l/4, phys slot l&3 holds logical slot (l&3)^((l>>3)&3)
  const int rl = lane >> 2;
  const int slg = (lane & 3) ^ ((lane >> 3) & 3);
  const int c0 = wid * 2, c1 = wid * 2 + 1;
  const size_t aR0 = (size_t)imin(m0 + c0 * 16 + rl, M - 1) * lda + slg * 8;
  const size_t aR1 = (size_t)imin(m0 + c1 * 16 + rl, M - 1) * lda + slg * 8;
  const size_t bR0 = (size_t)(n0 + c0 * 16 + rl) * ldb + slg * 8;
  const size_t bR1 = (size_t)(n0 + c1 * 16 + rl) * ldb + slg * 8;

  int aOff[4], bOff[4];
#pragma unroll
  for (int mi = 0; mi < 4; ++mi) aOff[mi] = (wm + mi * 16 + r) * 32 + ((g ^ ((r >> 1) & 3)) * 8);
#pragma unroll
  for (int ni = 0; ni < 4; ++ni) bOff[ni] = 4096 + (wn + ni * 16 + r) * 32 + ((g ^ ((r >> 1) & 3)) * 8);

  const int nt = kLen >> 6;  // K-tiles of 64

#define STAGE64(BI, T)                                          \
  do {                                                          \
    u16* bb = &sm[(BI) * 16384];                                \
    _Pragma("unroll") for (int h = 0; h < 2; ++h) {             \
      size_t kk = (size_t)(T) * 64 + h * 32;                    \
      glds16(A + aR0 + kk, bb + h * 8192 + c0 * 512);           \
      glds16(A + aR1 + kk, bb + h * 8192 + c1 * 512);           \
      glds16(Bt + bR0 + kk, bb + h * 8192 + 4096 + c0 * 512);   \
      glds16(Bt + bR1 + kk, bb + h * 8192 + 4096 + c1 * 512);   \
    }                                                           \
  } while (0)

  STAGE64(0, 0);

  for (int t = 0; t < nt; ++t) {
    WAITV0;                              // my 8 tile-t loads landed
    __builtin_amdgcn_s_barrier();        // tile-t published; tile-(t-1) reads retired
    SCHEDB;
    if (t + 1 < nt) STAGE64((t + 1) & 1, t + 1);  // lands during this tile's compute
    const u16* bb = &sm[(t & 1) * 16384];
#pragma unroll
    for (int h = 0; h < 2; ++h) {
      bf16x8 af[4], bfr[4];
#pragma unroll
      for (int mi = 0; mi < 4; ++mi) af[mi] = *(const bf16x8*)(bb + h * 8192 + aOff[mi]);
#pragma unroll
      for (int ni = 0; ni < 4; ++ni) bfr[ni] = *(const bf16x8*)(bb + h * 8192 + bOff[ni]);
      __builtin_amdgcn_s_setprio(1);
#pragma unroll
      for (int mi = 0; mi < 4; ++mi)
#pragma unroll
        for (int ni = 0; ni < 4; ++ni)
          acc[mi][ni] = __builtin_amdgcn_mfma_f32_16x16x32_bf16(af[mi], bfr[ni], acc[mi][ni], 0, 0, 0);
      __builtin_amdgcn_s_setprio(0);
    }
    SCHEDB;  // keep this tile's body ahead of next iteration's WAITV0
  }
#undef STAGE64

  if (role2)
    gemm_epi<EPI2>(acc, m0, n0, wm, wn, g, r, M, N, bias2, out2, resid2, modp,
                   goff2, rpb2, blockIdx.z, qb, kb, vtb);
  else
    gemm_epi<EPI1>(acc, m0, n0, wm, wn, g, r, M, N, bias1, out1, resid1, modp,
                   goff1, rpb1, blockIdx.z, qb, kb, vtb);
}

// ---- split-K reduce for mlp2 (x rows then c rows) ----
__global__ void k_red2(const u16* __restrict__ p0x, const u16* __restrict__ p1x,
                       const float* __restrict__ residx, const float* __restrict__ bx,
                       const u16* __restrict__ p0c, const u16* __restrict__ p1c,
                       const float* __restrict__ residc, const float* __restrict__ bc,
                       float* __restrict__ outx, float* __restrict__ outc) {
  int row = blockIdx.x;
  if (row < BB * NX) {
    size_t base = (size_t)row * DD;
#pragma unroll
    for (int i = 0; i < 6; ++i) {
      int j = threadIdx.x + 256 * i;
      outx[base + j] = residx[base + j] + bx[j] + bf2f(p0x[base + j]) + bf2f(p1x[base + j]);
    }
  } else {
    size_t base = (size_t)(row - BB * NX) * DD;
#pragma unroll
    for (int i = 0; i < 6; ++i) {
      int j = threadIdx.x + 256 * i;
      outc[base + j] = residc[base + j] + bc[j] + bf2f(p0c[base + j]) + bf2f(p1c[base + j]);
    }
  }
}

// ---- flash attention: QBLK=128 (8 waves x 16 rows), KBLK=64, HD=64 ----
// Swapped QK^T (S^T = mfma(K,Q)): lane owns q-row (lane&15), 16 in-lane t.
// In-register softmax, packed b64 P-writes, next-tile K/V register prefetch.
__global__ __launch_bounds__(512, 2) void k_attn(
    const u16* __restrict__ q, const u16* __restrict__ kk,
    const u16* __restrict__ vt, u16* __restrict__ ox, u16* __restrict__ oc) {
  __shared__ __align__(16) u16 Ks[64][72];
  __shared__ __align__(16) u16 Vs[64][72];
  __shared__ __align__(16) u16 Ps[8][16][72];

  const int lane = threadIdx.x & 63, wid = threadIdx.x >> 6;  // wid 0..7
  const int g = lane >> 4, r = lane & 15;
  const int q0 = blockIdx.x * 128;
  const int h = blockIdx.y, b = blockIdx.z;
  const size_t bh = (size_t)b * HH + h;
  const u16* qp = q + bh * (NT * 64);
  const u16* kp = kk + bh * (NT * 64);
  const u16* vp = vt + bh * (64 * NTP);

  const int qrow = imin(q0 + wid * 16 + r, NT - 1);
  u16x8 qr0 = *(const u16x8*)(qp + (size_t)qrow * 64 + g * 8);
  u16x8 qr1 = *(const u16x8*)(qp + (size_t)qrow * 64 + 32 + g * 8);
  bf16x8 qa0, qa1;
#pragma unroll
  for (int e = 0; e < 8; ++e) {
    qa0[e] = (short)f2bf(bf2f(qr0[e]) * 0.125f);
    qa1[e] = (short)f2bf(bf2f(qr1[e]) * 0.125f);
  }

  f32x4 oacc[4];
#pragma unroll
  for (int i = 0; i < 4; ++i) oacc[i] = fzero4();
  float mrow = -1e30f, lrow = 0.f;

  const int trA = threadIdx.x >> 3;
  const int ccA = (threadIdx.x & 7) * 8;

  u16x8 kreg, vreg;
#define LOADKV(T0)                                                     \
  do {                                                                 \
    int tsrc = imin((T0) + trA, NT - 1);                               \
    kreg = *(const u16x8*)(kp + (size_t)tsrc * 64 + ccA);              \
    int tcol = (T0) + ccA;                                             \
    if (tcol + 8 <= NT) {                                              \
      vreg = *(const u16x8*)(vp + (size_t)trA * NTP + tcol);           \
    } else {                                                           \
      _Pragma("unroll")                                                \
      for (int e = 0; e < 8; ++e)                                      \
        vreg[e] = vp[(size_t)trA * NTP + imin(tcol + e, NT - 1)];      \
    }                                                                  \
  } while (0)

  LOADKV(0);

  for (int t0 = 0; t0 < NT; t0 += 64) {
    if (t0) __syncthreads();
    *(u16x8*)&Ks[trA][ccA] = kreg;
    *(u16x8*)&Vs[trA][ccA] = vreg;
    __syncthreads();
    if (t0 + 64 < NT) LOADKV(t0 + 64);

    f32x4 s[4];
#pragma unroll
    for (int ni = 0; ni < 4; ++ni) {
      s[ni] = fzero4();
      s[ni] = __builtin_amdgcn_mfma_f32_16x16x32_bf16(*(const bf16x8*)&Ks[ni * 16 + r][g * 8], qa0, s[ni], 0, 0, 0);
      s[ni] = __builtin_amdgcn_mfma_f32_16x16x32_bf16(*(const bf16x8*)&Ks[ni * 16 + r][32 + g * 8], qa1, s[ni], 0, 0, 0);
    }

    float pv[4][4];
    float pm = -1e30f;
#pragma unroll
    for (int ni = 0; ni < 4; ++ni)
#pragma unroll
      for (int j = 0; j < 4; ++j) {
        int t = t0 + ni * 16 + g * 4 + j;
        float sv = (t < NT) ? s[ni][j] : -1e30f;
        pv[ni][j] = sv;
        pm = fmaxf(pm, sv);
      }
    pm = fmaxf(pm, __shfl_xor(pm, 16));
    pm = fmaxf(pm, __shfl_xor(pm, 32));

    float mn = fmaxf(mrow, pm);
    float alpha = __expf(mrow - mn);
    mrow = mn;
    float rs = 0.f;
#pragma unroll
    for (int ni = 0; ni < 4; ++ni)
#pragma unroll
      for (int j = 0; j < 4; ++j) {
        float p = __expf(pv[ni][j] - mn);
        pv[ni][j] = p;
        rs += p;
      }
    rs += __shfl_xor(rs, 16);
    rs += __shfl_xor(rs, 32);
    lrow = lrow * alpha + rs;

#pragma unroll
    for (int j = 0; j < 4; ++j) {
      float aj = __shfl(alpha, g * 4 + j);
#pragma unroll
      for (int ni = 0; ni < 4; ++ni) oacc[ni][j] *= aj;
    }

#pragma unroll
    for (int ni = 0; ni < 4; ++ni) {
      u32x2 w;
      w[0] = (u32)f2bf(pv[ni][0]) | ((u32)f2bf(pv[ni][1]) << 16);
      w[1] = (u32)f2bf(pv[ni][2]) | ((u32)f2bf(pv[ni][3]) << 16);
      *(u32x2*)&Ps[wid][r][ni * 16 + g * 4] = w;
    }

    bf16x8 pa0 = *(const bf16x8*)&Ps[wid][r][g * 8];
    bf16x8 pa1 = *(const bf16x8*)&Ps[wid][r][32 + g * 8];
#pragma unroll
    for (int ni = 0; ni < 4; ++ni) {
      oacc[ni] = __builtin_amdgcn_mfma_f32_16x16x32_bf16(pa0, *(const bf16x8*)&Vs[ni * 16 + r][g * 8], oacc[ni], 0, 0, 0);
      oacc[ni] = __builtin_amdgcn_mfma_f32_16x16x32_bf16(pa1, *(const bf16x8*)&Vs[ni * 16 + r][32 + g * 8], oacc[ni], 0, 0, 0);
    }
  }
#undef LOADKV

  float linv[4];
#pragma unroll
  for (int j = 0; j < 4; ++j) linv[j] = 1.f / __shfl(lrow, g * 4 + j);

#pragma unroll
  for (int ni = 0; ni < 4; ++ni)
#pragma unroll
    for (int j = 0; j < 4; ++j) {
      int tq = q0 + wid * 16 + g * 4 + j;
      if (tq >= NT) continue;
      float val = oacc[ni][j] * linv[j];
      int col = h * 64 + ni * 16 + r;
      if (tq < NX)
        ox[(size_t)(b * NX + tq) * DD + col] = f2bf(val);
      else
        oc[(size_t)(b * NC + tq - NX) * DD + col] = f2bf(val);
    }
}

extern "C" void kernel_launch(void* const* d_in, const int* in_sizes, int n_in,
                              void* d_out, int out_size, void* d_ws, size_t ws_size,
                              hipStream_t stream) {
  const float* x = (const float*)d_in[0];
  const float* c = (const float*)d_in[1];
  const float* vec = (const float*)d_in[2];
  const float* w_mod = (const float*)d_in[3];
  const float* b_mod = (const float*)d_in[4];
  const float* w_qkv_x = (const float*)d_in[5];
  const float* b_qkv_x = (const float*)d_in[6];
  const float* w_qkv_c = (const float*)d_in[7];
  const float* b_qkv_c = (const float*)d_in[8];
  const float* w_proj_x = (const float*)d_in[9];
  const float* b_proj_x = (const float*)d_in[10];
  const float* w_proj_c = (const float*)d_in[11];
  const float* b_proj_c = (const float*)d_in[12];
  const float* w1_x = (const float*)d_in[13];
  const float* b1_x = (const float*)d_in[14];
  const float* w2_x = (const float*)d_in[15];
  const float* b2_x = (const float*)d_in[16];
  const float* w1_c = (const float*)d_in[17];
  const float* b1_c = (const float*)d_in[18];
  const float* w2_c = (const float*)d_in[19];
  const float* b2_c = (const float*)d_in[20];

  if (ws_size < 229195776ull) return;  // workspace layout below needs this much

  char* ws = (char*)d_ws;
  // persistent: bf16-transposed weights + mod
  u16* wt_qkv_x = (u16*)(ws + 0);
  u16* wt_qkv_c = (u16*)(ws + 14155776);
  u16* wt_proj_x = (u16*)(ws + 28311552);
  u16* wt_proj_c = (u16*)(ws + 33030144);
  u16* wt_w1_x = (u16*)(ws + 37748736);
  u16* wt_w1_c = (u16*)(ws + 56623104);
  u16* wt_w2_x = (u16*)(ws + 75497472);
  u16* wt_w2_c = (u16*)(ws + 94371840);
  float* modf = (float*)(ws + 113246208);
  char* S = ws + 113393664;
  // slot 1 (14,475,264 B): x_n/c_n -> o_x/o_c -> xln/cln -> pb0 + pc0
  u16* xn = (u16*)(S);
  u16* cn = (u16*)(S + 12582912);
  // slot 2 (43,425,792 B): x2/c2 (f32); pb1 follows, then pc1 gap
  float* x2 = (float*)(S + 14475264);   // 25,165,824 B, ends S+39,641,088
  float* c2 = (float*)(S + 39641088);   //  3,784,704 B, ends S+43,425,792
  u16* pb0 = (u16*)(S);                 // 12,582,912 B (xn dead after mlp1 reads)
  u16* pc0 = (u16*)(S + 12582912);      //  1,892,352 B (cn dead after mlp1 reads)
  u16* pb1 = (u16*)(S + 43425792);      // 12,582,912 B (dead region after c2)
  u16* pc1 = (u16*)(S + 56008704);      //  1,892,352 B (gap before slot 3)
  const int PSTRIDE = 43425792 / 2;     // u16 stride pb0->pb1 AND pc0->pc1
  // slot 3 (57,901,056 B): q/k/vt -> h_x/h_c ; head also used as k_mod partials
  u16* qb = (u16*)(S + 57901056);
  u16* kb = (u16*)(S + 72376320);
  u16* vtb = (u16*)(S + 86851584);
  u16* hx = (u16*)(S + 57901056);
  u16* hc = (u16*)(S + 108232704);
  float* modpart = (float*)(S + 57901056);  // dead before q/k/vt written

  // 1) all 8 weight transposes in one dispatch
  {
    TDesc d;
    const float* Ws[8] = {w_qkv_x, w_qkv_c, w_proj_x, w_proj_c, w1_x, w1_c, w2_x, w2_c};
    u16* Wts[8] = {wt_qkv_x, wt_qkv_c, wt_proj_x, wt_proj_c, wt_w1_x, wt_w1_c, wt_w2_x, wt_w2_c};
    int Ks[8] = {DD, DD, DD, DD, DD, DD, MHD, MHD};
    int Ns[8] = {NQKV, NQKV, DD, DD, MHD, MHD, DD, DD};
    int off = 0;
    for (int i = 0; i < 8; ++i) {
      d.W[i] = Ws[i]; d.Wt[i] = Wts[i]; d.K[i] = Ks[i]; d.N[i] = Ns[i];
      d.off[i] = off;
      off += (Ns[i] >> 5) * (Ks[i] >> 5);
    }
    d.off[8] = off;
    k_transpose8<<<dim3(off), 256, 0, stream>>>(d);
  }

  // 2) modulation vector (split-K, deterministic two-stage)
  k_mod_part<<<dim3(NMOD / 256, KSPL), 256, 0, stream>>>(vec, w_mod, modpart);
  k_mod_red<<<dim3(NMOD / 256), 256, 0, stream>>>(modpart, b_mod, modf);

  // 3) modulated LN (x+c merged) -> bf16
  k_ln2<<<dim3(BB * (NX + NC)), 256, 0, stream>>>(x, xn, c, cn, modf, 0, DD, 3 * DD, 4 * DD);

  // 4) merged QKV GEMM (x+c) with scatter epilogue -> qb,kb,vtb directly
  k_gemm2<5, 5><<<dim3(NQKV / 128, 37), 256, 0, stream>>>(
      xn, wt_qkv_x, b_qkv_x, BB * NX, NX, 0, DD,
      cn, wt_qkv_c, b_qkv_c, BB * NC, NC, NX, DD,
      32, NQKV, DD, DD, 0, nullptr, nullptr, nullptr, nullptr, nullptr,
      qb, kb, vtb);

  // 5) flash attention (QBLK=128, 8 waves) -> o (written into slot 1)
  k_attn<<<dim3((NT + 127) / 128, HH, BB), 512, 0, stream>>>(qb, kb, vtb, xn, cn);

  // 6) merged output projections with gated residual -> x2/c2 f32
  k_gemm2<2, 2><<<dim3(DD / 128, 37), 256, 0, stream>>>(
      xn, wt_proj_x, b_proj_x, BB * NX, NX, 2 * DD, DD,
      cn, wt_proj_c, b_proj_c, BB * NC, NC, 5 * DD, DD,
      32, DD, DD, DD, 0, x2, c2, x, c, modf, nullptr, nullptr, nullptr);

  // 7) plain LN (x+c merged) -> bf16
  k_ln2<<<dim3(BB * (NX + NC)), 256, 0, stream>>>(x2, xn, c2, cn, nullptr, 0, 0, 0, 0);

  // 8) merged MLP-1 (gelu) -> hx/hc
  k_gemm2<1, 1><<<dim3(MHD / 128, 37), 256, 0, stream>>>(
      xn, wt_w1_x, b1_x, BB * NX, NX, 0, DD,
      cn, wt_w1_c, b1_c, BB * NC, NC, 0, DD,
      32, MHD, DD, DD, 0, hx, hc, nullptr, nullptr, nullptr, nullptr, nullptr, nullptr);

  float* outx = (float*)d_out;
  float* outc = outx + (size_t)BB * NX * DD;
  // 9) merged MLP-2: BOTH streams split-K over z (48 K-tiles every block)
  k_gemm2<4, 4><<<dim3(DD / 128, 37, 2), 256, 0, stream>>>(
      hx, wt_w2_x, b2_x, BB * NX, NX, PSTRIDE, MHD / 2,
      hc, wt_w2_c, b2_c, BB * NC, NC, PSTRIDE, MHD / 2,
      32, DD, MHD, MHD, MHD / 2, pb0, pc0, nullptr, nullptr, nullptr,
      nullptr, nullptr, nullptr);
  k_red2<<<dim3(BB * (NX + NC)), 256, 0, stream>>>(
      pb0, pb1, x2, b2_x, pc0, pc1, c2, b2_c, outx, outc);
}